// Round 14
// baseline (544.572 us; speedup 1.0000x reference)
//
#include <hip/hip_runtime.h>
#include <hip/hip_bf16.h>

#define N_NODES 32768
#define N_EDGES 524288
#define LN_EPS 1e-5f

typedef unsigned short ushort_t;
typedef __attribute__((ext_vector_type(8))) short short8v;
typedef __attribute__((ext_vector_type(4))) float float4v;
typedef __attribute__((ext_vector_type(2))) float float2v;

__device__ __forceinline__ float bf2f(ushort_t u) {
    return __uint_as_float(((unsigned int)u) << 16);
}
__device__ __forceinline__ ushort_t f2bf(float f) {
    unsigned int u = __float_as_uint(f);
    unsigned int r = (u + 0x7FFFu + ((u >> 16) & 1u)) >> 16;
    return (ushort_t)r;
}
__device__ __forceinline__ float lo16(unsigned int x) { return __uint_as_float(x << 16); }
__device__ __forceinline__ float hi16(unsigned int x) { return __uint_as_float(x & 0xFFFF0000u); }

#if __has_builtin(__builtin_amdgcn_exp2f)
#define EXP2(x) __builtin_amdgcn_exp2f(x)
#else
#define EXP2(x) exp2f(x)
#endif

// conv-region element offsets (f32 scratch holding all weight tensors)
#define OFF_WNODE 0
#define OFF_BNODE 5632
#define OFF_WPOS  5760
#define OFF_BPOS  6784
#define OFF_WEDGE 6912
#define OFF_BEDGE 7040
#define OFF_WQ    7168
#define OFF_WK    56320
#define OFF_WV    105472
#define OFF_WE    154624
#define OFF_WLIN  203776
#define OFF_BLIN  252928
#define OFF_G1    253312
#define OFF_BE1   253696
#define OFF_WF1   254080
#define OFF_BF1   352384
#define OFF_WF2   353152
#define OFF_BF2   451456
#define OFF_G2    451840
#define OFF_BE2   452224
#define CONV_TOTAL 452608

// swizzled-B record bases (records of 512 ushorts = 64 lanes x 8 bf16)
#define REC_QKV(i)  ((i) * 96)          // 24 ct x 4 kb
#define REC_WLIN(i) (288 + (i) * 32)    // 8 ct x 4 kb
#define REC_WF1(i)  (384 + (i) * 64)    // 16 ct x 4 kb
#define REC_WF2(i)  (576 + (i) * 64)    // 8 ct x 8 kb
#define REC_TOTAL   768

#define LDS_STRIDE 264   // ushorts per LDS row (256 + 8 pad)
#define LDS_FSTRIDE 132  // floats per LDS row (same byte footprint)

// ---------------- dtype detection: bf16 data has exponent-like bits at [15:8] ---------
__global__ void detect_kernel(const unsigned int* __restrict__ wn, int* __restrict__ flag) {
    __shared__ int s[256];
    int t = threadIdx.x;
    int cnt = 0;
    for (int i = t; i < 2816; i += 256) {
        unsigned int b = (wn[i] >> 8) & 0x7F;
        cnt += (b >= 0x3A && b <= 0x40) ? 1 : 0;
    }
    s[t] = cnt;
    __syncthreads();
    for (int off = 128; off > 0; off >>= 1) {
        if (t < off) s[t] += s[t + off];
        __syncthreads();
    }
    if (t == 0) *flag = (s[0] > 1408) ? 1 : 0;   // 1 = bf16, 0 = f32
}

// ---------------- canonicalize all weight buffers to f32 scratch ----------------------
struct ConvArgs { const void* src[20]; };

__global__ void convert_kernel(ConvArgs a, const int* __restrict__ flag,
                               float* __restrict__ dst) {
    int gid = blockIdx.x * 256 + threadIdx.x;
    if (gid >= CONV_TOTAL) return;
    const int off[21] = {OFF_WNODE, OFF_BNODE, OFF_WPOS, OFF_BPOS, OFF_WEDGE, OFF_BEDGE,
                         OFF_WQ, OFF_WK, OFF_WV, OFF_WE, OFF_WLIN, OFF_BLIN, OFF_G1,
                         OFF_BE1, OFF_WF1, OFF_BF1, OFF_WF2, OFF_BF2, OFF_G2, OFF_BE2,
                         CONV_TOTAL};
    int s = 0;
#pragma unroll
    for (int i = 1; i < 20; ++i) s += (gid >= off[i]) ? 1 : 0;
    int local = gid - off[s];
    if (*flag)
        dst[gid] = bf2f(((const ushort_t*)a.src[s])[local]);
    else
        dst[gid] = ((const float*)a.src[s])[local];
}

// ---------------- swizzle GEMM weights into MFMA B-fragment records -------------------
// record(ct,kb): lane l holds W[kb*32 + (l>>4)*8 + j][ct*16 + (l&15)], j=0..7
__global__ void swz_kernel(const float* __restrict__ conv, ushort_t* __restrict__ swz) {
    int gid = blockIdx.x * 256 + threadIdx.x;   // REC_TOTAL*64 threads
    int lane = gid & 63;
    int rec = gid >> 6;
    if (rec >= REC_TOTAL) return;
    int col = lane & 15, quad = lane >> 4;
    const float* src;
    int ct, kb, OC;
    if (rec < 288) {                       // QKV: 3 layers x 24ct x 4kb
        int layer = rec / 96, r2 = rec % 96;
        ct = r2 >> 2; kb = r2 & 3;
        int seg = ct >> 3;                 // 0=Wq 1=Wk 2=Wv
        int base = (seg == 0 ? OFF_WQ : (seg == 1 ? OFF_WK : OFF_WV)) + layer * 16384;
        src = conv + base; OC = 128; ct &= 7;
    } else if (rec < 384) {                // W_lin
        int r = rec - 288, layer = r / 32, r2 = r % 32;
        ct = r2 >> 2; kb = r2 & 3;
        src = conv + OFF_WLIN + layer * 16384; OC = 128;
    } else if (rec < 576) {                // Wf1 (OC=256)
        int r = rec - 384, layer = r / 64, r2 = r % 64;
        ct = r2 >> 2; kb = r2 & 3;
        src = conv + OFF_WF1 + layer * 32768; OC = 256;
    } else {                               // Wf2 (K=256)
        int r = rec - 576, layer = r / 64, r2 = r % 64;
        ct = r2 >> 3; kb = r2 & 7;
        src = conv + OFF_WF2 + layer * 32768; OC = 128;
    }
    int n = ct * 16 + col;
    ushort_t v[8];
#pragma unroll
    for (int j = 0; j < 8; ++j) v[j] = f2bf(src[(size_t)(kb * 32 + quad * 8 + j) * OC + n]);
    ushort_t* o = swz + (size_t)rec * 512 + lane * 8;
#pragma unroll
    for (int j = 0; j < 8; ++j) o[j] = v[j];
}

// ---------------- input projection -> h f32 + hb bf16 ---------------------------------
__global__ void input_proj_kernel(const void* __restrict__ feats,
                                  const void* __restrict__ lap,
                                  const float* __restrict__ conv,
                                  const int* __restrict__ flag,
                                  float* __restrict__ h, ushort_t* __restrict__ hb) {
    int gid = blockIdx.x * 256 + threadIdx.x;   // N*32 threads
    int node = gid >> 5;
    int cg = (gid & 31) * 4;
    bool isbf = (*flag != 0);
    const float* Wn = conv + OFF_WNODE;
    const float* Wp = conv + OFF_WPOS;

    float4 b1 = *(const float4*)(conv + OFF_BNODE + cg);
    float4 b2 = *(const float4*)(conv + OFF_BPOS + cg);
    float a0 = b1.x + b2.x, a1 = b1.y + b2.y, a2 = b1.z + b2.z, a3 = b1.w + b2.w;

#define ACC(fv, Wbase, kk)                                            \
    {                                                                 \
        float4 wv_ = *(const float4*)(Wbase + (size_t)(kk) * 128 + cg); \
        a0 = fmaf(fv, wv_.x, a0);                                     \
        a1 = fmaf(fv, wv_.y, a1);                                     \
        a2 = fmaf(fv, wv_.z, a2);                                     \
        a3 = fmaf(fv, wv_.w, a3);                                     \
    }

    if (isbf) {
        const ushort_t* frow = (const ushort_t*)feats + (size_t)node * 44;
        const ushort_t* prow = (const ushort_t*)lap + (size_t)node * 8;
#pragma unroll
        for (int i = 0; i < 11; ++i) {
            ushort4 f = *(const ushort4*)(frow + i * 4);
            ACC(bf2f(f.x), Wn, i * 4 + 0)
            ACC(bf2f(f.y), Wn, i * 4 + 1)
            ACC(bf2f(f.z), Wn, i * 4 + 2)
            ACC(bf2f(f.w), Wn, i * 4 + 3)
        }
#pragma unroll
        for (int i = 0; i < 2; ++i) {
            ushort4 f = *(const ushort4*)(prow + i * 4);
            ACC(bf2f(f.x), Wp, i * 4 + 0)
            ACC(bf2f(f.y), Wp, i * 4 + 1)
            ACC(bf2f(f.z), Wp, i * 4 + 2)
            ACC(bf2f(f.w), Wp, i * 4 + 3)
        }
    } else {
        const float4* frow = (const float4*)((const float*)feats + (size_t)node * 44);
        const float4* prow = (const float4*)((const float*)lap + (size_t)node * 8);
#pragma unroll
        for (int i = 0; i < 11; ++i) {
            float4 f = frow[i];
            ACC(f.x, Wn, i * 4 + 0)
            ACC(f.y, Wn, i * 4 + 1)
            ACC(f.z, Wn, i * 4 + 2)
            ACC(f.w, Wn, i * 4 + 3)
        }
#pragma unroll
        for (int i = 0; i < 2; ++i) {
            float4 f = prow[i];
            ACC(f.x, Wp, i * 4 + 0)
            ACC(f.y, Wp, i * 4 + 1)
            ACC(f.z, Wp, i * 4 + 2)
            ACC(f.w, Wp, i * 4 + 3)
        }
    }
#undef ACC

    size_t idx = (size_t)node * 128 + cg;
    *(float4*)(h + idx) = make_float4(a0, a1, a2, a3);
    ushort4 ob;
    ob.x = f2bf(a0); ob.y = f2bf(a1); ob.z = f2bf(a2); ob.w = f2bf(a3);
    *(ushort4*)(hb + idx) = ob;
}

// ---------------- u_l, c1_l for the collapsed edge GEMM -------------------------------
// Pre-scaled by (1/sqrt(dk))*log2(e): agg works in the log2 domain with raw v_exp.
__global__ void uc_kernel(const float* __restrict__ conv,
                          float* __restrict__ u, float* __restrict__ c1) {
    int l = blockIdx.x;
    int d = threadIdx.x;
    const float* W_edge = conv + OFF_WEDGE;
    const float* b_edge = conv + OFF_BEDGE;
    const float* Wl = conv + OFF_WE + l * 128 * 128;
    float uu = 0.f, cc = 0.f;
#pragma unroll 4
    for (int k = 0; k < 128; ++k) {
        float w = Wl[k * 128 + d];
        uu += W_edge[k] * w;
        cc += b_edge[k] * w;
    }
    const float scale = 0.17677669529663687f * 1.4426950408889634f;  // isq * log2(e)
    u[l * 128 + d] = uu * scale;
    c1[l * 128 + d] = (1.f + cc) * scale;
}

// ---------------- CSR build ------------------------------------------------------------
__global__ void hist_kernel(const int* __restrict__ dst, int* __restrict__ deg) {
    int e = blockIdx.x * 256 + threadIdx.x;
    if (e < N_EDGES) atomicAdd(&deg[dst[e]], 1);
}

__global__ void scan_kernel(const int* __restrict__ deg, int* __restrict__ rowstart,
                            int* __restrict__ cursor) {
    __shared__ int lds[1024];
    int t = threadIdx.x;
    int base = t * 32;
    int v[32];
    int csum = 0;
#pragma unroll
    for (int j = 0; j < 32; ++j) { v[j] = deg[base + j]; csum += v[j]; }
    lds[t] = csum;
    __syncthreads();
    for (int off = 1; off < 1024; off <<= 1) {
        int x = (t >= off) ? lds[t - off] : 0;
        __syncthreads();
        lds[t] += x;
        __syncthreads();
    }
    int excl = lds[t] - csum;
    int running = excl;
#pragma unroll
    for (int j = 0; j < 32; ++j) {
        rowstart[base + j] = running;
        cursor[base + j] = running;
        running += v[j];
    }
    if (t == 1023) rowstart[N_NODES] = running;
}

__global__ void scatter_kernel(const int* __restrict__ src, const int* __restrict__ dst,
                               const void* __restrict__ ef, const int* __restrict__ flag,
                               int* __restrict__ cursor,
                               unsigned int* __restrict__ edges) {
    int e = blockIdx.x * 256 + threadIdx.x;
    if (e < N_EDGES) {
        ushort_t efb = (*flag != 0) ? ((const ushort_t*)ef)[e]
                                    : f2bf(((const float*)ef)[e]);
        int d = dst[e];
        int p = atomicAdd(&cursor[d], 1);
        edges[p] = (unsigned int)src[e] | ((unsigned int)efb << 16);
    }
}

// ---------------- fused QKV: one wave per 16 rows, all 384 cols -----------------------
// A (hb) read ONCE; 24 ct-tiles (Q:0-7, K:8-15, V:16-23); outputs staged in LDS then
// stored fully coalesced: Q bf16 [N,128], KV fp8-packed [N,256B]
// (per 8-dim block b: bytes 16b..+7 = K dims, +8..+15 = V dims).
__global__ __launch_bounds__(64, 2) void qkv_kernel(
    const ushort_t* __restrict__ A,
    const ushort_t* __restrict__ Bswz,
    ushort_t* __restrict__ outQ,
    unsigned char* __restrict__ outKV) {
    __shared__ ushort_t lds[16 * LDS_STRIDE];   // per row: [0..127]=Q us, [128..255]=KV us
    const int lane = threadIdx.x & 63;
    const int col = lane & 15, quad = lane >> 4;
    const int m0 = blockIdx.x * 16;
    const int lrowc = quad * 4;

    // A-fragments (4 x 16x16x32 K-blocks)
    short8v af[4];
    const ushort_t* Ap = A + (size_t)(m0 + col) * 128 + quad * 8;
#pragma unroll
    for (int kb = 0; kb < 4; ++kb)
        af[kb] = *(const short8v*)(Ap + kb * 32);

    float4v acc[24];
#pragma unroll
    for (int ct = 0; ct < 24; ++ct) acc[ct] = (float4v){0.f, 0.f, 0.f, 0.f};
#pragma unroll
    for (int kb = 0; kb < 4; ++kb) {
#pragma unroll
        for (int ct = 0; ct < 24; ++ct) {
            short8v b = *(const short8v*)(Bswz + (size_t)(ct * 4 + kb) * 512 + lane * 8);
            acc[ct] = __builtin_amdgcn_mfma_f32_16x16x32_bf16(af[kb], b, acc[ct], 0, 0, 0);
        }
    }

    // ---- stage Q (bf16) ----
#pragma unroll
    for (int ct = 0; ct < 8; ++ct) {
        int j = ct * 16 + col;
#pragma unroll
        for (int r = 0; r < 4; ++r)
            lds[(lrowc + r) * LDS_STRIDE + j] = f2bf(acc[ct][r]);
    }
    // ---- stage K/V (fp8 pairs; even-col lanes write packed ushort) ----
#pragma unroll
    for (int seg = 0; seg < 2; ++seg) {          // 0 = K (ct 8..15), 1 = V (ct 16..23)
#pragma unroll
        for (int c = 0; c < 8; ++c) {
            int ct = 8 + seg * 8 + c;
            int j = c * 16 + col;                // dim 0..127
#pragma unroll
            for (int r = 0; r < 4; ++r) {
                float a = acc[ct][r];
                float b = __shfl_xor(a, 1, 64);  // partner dim j^1
                if ((col & 1) == 0) {
                    unsigned short pk = (unsigned short)
                        __builtin_amdgcn_cvt_pk_fp8_f32(a, b, 0, false);
                    int us = (j >> 3) * 8 + ((j >> 1) & 3) + seg * 4;  // ushort idx in KV
                    lds[(lrowc + r) * LDS_STRIDE + 128 + us] = pk;
                }
            }
        }
    }
    __syncthreads();   // single-wave block: lgkmcnt wait only

    // ---- coalesced stores: Q 16 rows x 16 uint4; KV 16 rows x 16 uint4 ----
#pragma unroll
    for (int jj = 0; jj < 4; ++jj) {
        int p = lane + jj * 64;        // 0..255
        int row = p >> 4;
        int c16 = p & 15;
        uint4 qv = *(const uint4*)&lds[row * LDS_STRIDE + c16 * 8];
        *(uint4*)&outQ[(size_t)(m0 + row) * 128 + c16 * 8] = qv;
    }
#pragma unroll
    for (int jj = 0; jj < 4; ++jj) {
        int p = lane + jj * 64;
        int row = p >> 4;
        int c16 = p & 15;
        uint4 kv = *(const uint4*)&lds[row * LDS_STRIDE + 128 + c16 * 8];
        *(uint4*)&outKV[(size_t)(m0 + row) * 256 + c16 * 16] = kv;
    }
}

// ---------------- fused layer tail: h = LN2(h' + relu(h'@Wf1+b)@Wf2+b2),
//                  h' = LN1(h + HOUT@WL+bl). One wave per 16 rows (grid N/16).
__global__ __launch_bounds__(64, 2) void ffn_kernel(
    const ushort_t* __restrict__ HOUT,   // [N,128] bf16 (= hb, attention out)
    const ushort_t* __restrict__ BWL,    // swz W_lin  (8ct x 4kb)
    const ushort_t* __restrict__ BF1,    // swz Wf1    (16ct x 4kb)
    const ushort_t* __restrict__ BF2,    // swz Wf2    (8ct x 8kb)
    const float* __restrict__ bl,
    const float* __restrict__ g1v, const float* __restrict__ be1v,
    const float* __restrict__ bf1v,
    const float* __restrict__ bf2v,
    const float* __restrict__ g2v, const float* __restrict__ be2v,
    float* __restrict__ h,               // [N,128] f32 in-out (residual -> final)
    ushort_t* __restrict__ hb) {         // [N,128] bf16 out
    __shared__ __align__(16) char ldsraw[16 * 528];   // 8448 B, dual-view
    ushort_t* ldsu = (ushort_t*)ldsraw;  // stride LDS_STRIDE (264)
    float* ldsf = (float*)ldsraw;        // stride LDS_FSTRIDE (132)
    const int lane = threadIdx.x & 63;
    const int col = lane & 15, quad = lane >> 4;
    const int m0 = blockIdx.x * 16;
    const int rowb = m0 + quad * 4;          // global row base (C-layout)
    const int lrowc = quad * 4;              // LDS row base for C-layout stores
    const int lrowa = col;                   // LDS row for A-fragment reads

    // ---- GEMM1: HOUT @ W_lin ----
    float4v acc[8];
#pragma unroll
    for (int ct = 0; ct < 8; ++ct) acc[ct] = (float4v){0.f, 0.f, 0.f, 0.f};
    const ushort_t* Ap = HOUT + (size_t)(m0 + col) * 128 + quad * 8;
#pragma unroll
    for (int kb = 0; kb < 4; ++kb) {
        short8v a = *(const short8v*)(Ap + kb * 32);
#pragma unroll
        for (int ct = 0; ct < 8; ++ct) {
            short8v b = *(const short8v*)(BWL + (size_t)(ct * 4 + kb) * 512 + lane * 8);
            acc[ct] = __builtin_amdgcn_mfma_f32_16x16x32_bf16(a, b, acc[ct], 0, 0, 0);
        }
    }

    // ---- LN1 (+bias, +residual h) -> val (h', kept in registers) ----
    float val[8][4], s[4] = {0.f, 0.f, 0.f, 0.f}, ss[4] = {0.f, 0.f, 0.f, 0.f};
#pragma unroll
    for (int ct = 0; ct < 8; ++ct) {
        float bi = bl[ct * 16 + col];
#pragma unroll
        for (int r = 0; r < 4; ++r) {
            float v = acc[ct][r] + bi + h[(size_t)(rowb + r) * 128 + ct * 16 + col];
            val[ct][r] = v;
            s[r] += v;
            ss[r] += v * v;
        }
    }
#pragma unroll
    for (int mask = 1; mask < 16; mask <<= 1) {
#pragma unroll
        for (int r = 0; r < 4; ++r) {
            s[r] += __shfl_xor(s[r], mask, 64);
            ss[r] += __shfl_xor(ss[r], mask, 64);
        }
    }
#pragma unroll
    for (int r = 0; r < 4; ++r) {
        float mean = s[r] * (1.f / 128.f);
        float var = ss[r] * (1.f / 128.f) - mean * mean;
        s[r] = mean;
        ss[r] = rsqrtf(var + LN_EPS);
    }
#pragma unroll
    for (int ct = 0; ct < 8; ++ct) {
        float gg = g1v[ct * 16 + col], bb = be1v[ct * 16 + col];
#pragma unroll
        for (int r = 0; r < 4; ++r) {
            float o = (val[ct][r] - s[r]) * ss[r] * gg + bb;
            val[ct][r] = o;                                      // residual for LN2
            ldsu[(lrowc + r) * LDS_STRIDE + ct * 16 + col] = f2bf(o);
        }
    }
    __syncthreads();

    // ---- A-fragments of h' from LDS ----
    short8v af[4];
#pragma unroll
    for (int kb = 0; kb < 4; ++kb)
        af[kb] = *(const short8v*)&ldsu[lrowa * LDS_STRIDE + kb * 32 + quad * 8];

    // ---- GEMM2: h' @ Wf1 (OC=256) ----
    float4v acc2[16];
#pragma unroll
    for (int ct = 0; ct < 16; ++ct) acc2[ct] = (float4v){0.f, 0.f, 0.f, 0.f};
#pragma unroll
    for (int kb = 0; kb < 4; ++kb) {
#pragma unroll
        for (int ct = 0; ct < 16; ++ct) {
            short8v b = *(const short8v*)(BF1 + (size_t)(ct * 4 + kb) * 512 + lane * 8);
            acc2[ct] = __builtin_amdgcn_mfma_f32_16x16x32_bf16(af[kb], b, acc2[ct], 0, 0, 0);
        }
    }
    __syncthreads();

    // ---- T = relu(acc2 + bf1) -> LDS ----
#pragma unroll
    for (int ct = 0; ct < 16; ++ct) {
        float bi = bf1v[ct * 16 + col];
#pragma unroll
        for (int r = 0; r < 4; ++r) {
            float v = fmaxf(acc2[ct][r] + bi, 0.f);
            ldsu[(lrowc + r) * LDS_STRIDE + ct * 16 + col] = f2bf(v);
        }
    }
    __syncthreads();

    // ---- GEMM3: T @ Wf2 (K=256) ----
    float4v acc3[8];
#pragma unroll
    for (int ct = 0; ct < 8; ++ct) acc3[ct] = (float4v){0.f, 0.f, 0.f, 0.f};
#pragma unroll
    for (int kb = 0; kb < 8; ++kb) {
        short8v a = *(const short8v*)&ldsu[lrowa * LDS_STRIDE + kb * 32 + quad * 8];
#pragma unroll
        for (int ct = 0; ct < 8; ++ct) {
            short8v b = *(const short8v*)(BF2 + (size_t)(ct * 8 + kb) * 512 + lane * 8);
            acc3[ct] = __builtin_amdgcn_mfma_f32_16x16x32_bf16(a, b, acc3[ct], 0, 0, 0);
        }
    }

    // ---- LN2 (+bias, +residual h') ----
    float s2[4] = {0.f, 0.f, 0.f, 0.f}, ss2[4] = {0.f, 0.f, 0.f, 0.f};
#pragma unroll
    for (int ct = 0; ct < 8; ++ct) {
        float bi = bf2v[ct * 16 + col];
#pragma unroll
        for (int r = 0; r < 4; ++r) {
            float v = acc3[ct][r] + bi + val[ct][r];
            val[ct][r] = v;
            s2[r] += v;
            ss2[r] += v * v;
        }
    }
#pragma unroll
    for (int mask = 1; mask < 16; mask <<= 1) {
#pragma unroll
        for (int r = 0; r < 4; ++r) {
            s2[r] += __shfl_xor(s2[r], mask, 64);
            ss2[r] += __shfl_xor(ss2[r], mask, 64);
        }
    }
#pragma unroll
    for (int r = 0; r < 4; ++r) {
        float mean = s2[r] * (1.f / 128.f);
        float var = ss2[r] * (1.f / 128.f) - mean * mean;
        s2[r] = mean;
        ss2[r] = rsqrtf(var + LN_EPS);
    }
    __syncthreads();   // T fully consumed; reuse LDS as f32 staging
#pragma unroll
    for (int ct = 0; ct < 8; ++ct) {
        float gg = g2v[ct * 16 + col], bb = be2v[ct * 16 + col];
#pragma unroll
        for (int r = 0; r < 4; ++r) {
            float o = (val[ct][r] - s2[r]) * ss2[r] * gg + bb;
            ldsf[(lrowc + r) * LDS_FSTRIDE + ct * 16 + col] = o;
        }
    }
    __syncthreads();

    // ---- coalesced stores: h as float4, hb as uint4 (8 bf16) ----
#pragma unroll
    for (int j = 0; j < 8; ++j) {
        int p = lane + j * 64;        // 0..511
        int row = p >> 5;
        int c4 = p & 31;
        float4 vv = *(const float4*)&ldsf[row * LDS_FSTRIDE + c4 * 4];
        *(float4*)&h[(size_t)(m0 + row) * 128 + c4 * 4] = vv;
    }
#pragma unroll
    for (int j = 0; j < 4; ++j) {
        int p = lane + j * 64;        // 0..255
        int row = p >> 4;
        int c8 = p & 15;
        float4 va = *(const float4*)&ldsf[row * LDS_FSTRIDE + c8 * 8];
        float4 vb = *(const float4*)&ldsf[row * LDS_FSTRIDE + c8 * 8 + 4];
        uint4 ou;
        ou.x = (unsigned)f2bf(va.x) | ((unsigned)f2bf(va.y) << 16);
        ou.y = (unsigned)f2bf(va.z) | ((unsigned)f2bf(va.w) << 16);
        ou.z = (unsigned)f2bf(vb.x) | ((unsigned)f2bf(vb.y) << 16);
        ou.w = (unsigned)f2bf(vb.z) | ((unsigned)f2bf(vb.w) << 16);
        *(uint4*)&hb[(size_t)(m0 + row) * 128 + c8 * 8] = ou;
    }
}

// ---------------- attention aggregation --------------------------------------------
// One WAVE per dst node. 4 edge-groups x 16 lanes; lane covers 8 dims (sub = lane&15).
// Q bf16 [N,128]; K/V fp8-e4m3 packed [N,256B] -> ONE uint4 gather per edge per lane.
// Log2-domain lazy-max online softmax (u/c1 pre-scaled by isq*log2e).
__global__ __launch_bounds__(64) void agg_kernel(
    const ushort_t* __restrict__ Q, const unsigned char* __restrict__ KV,
    const int* __restrict__ rowstart, const unsigned int* __restrict__ edges,
    const float* __restrict__ u, const float* __restrict__ c1,
    ushort_t* __restrict__ hout) {
    const int lane = threadIdx.x & 63;
    const int v = blockIdx.x;
    const int sub = lane & 15;
    const int grp = lane >> 4;

    // Q dims 8sub..+7 (uint4 = 8 bf16)
    uint4 qu = *(const uint4*)(Q + (size_t)v * 128 + sub * 8);
    float q0 = lo16(qu.x), q1 = hi16(qu.x), q2 = lo16(qu.y), q3 = hi16(qu.y);
    float q4 = lo16(qu.z), q5 = hi16(qu.z), q6 = lo16(qu.w), q7 = hi16(qu.w);
    float4 uva = *(const float4*)(u + sub * 8);
    float4 uvb = *(const float4*)(u + sub * 8 + 4);
    float4 cva = *(const float4*)(c1 + sub * 8);
    float4 cvb = *(const float4*)(c1 + sub * 8 + 4);

    float m = -1.0e38f;
    float sA[8] = {0.f, 0.f, 0.f, 0.f, 0.f, 0.f, 0.f, 0.f};
    float o[8] = {0.f, 0.f, 0.f, 0.f, 0.f, 0.f, 0.f, 0.f};

    const int start = rowstart[v];
    const int deg = rowstart[v + 1] - start;
    const int nfull = deg >> 2;
    const unsigned int* ep = edges + start + grp;

#define AGG_BODY(PE, MASKED, VALID)                                              \
    {                                                                            \
        unsigned int pe_ = (PE);                                                 \
        int s_ = (int)(pe_ & 0xFFFFu);                                           \
        float ef_ = __uint_as_float(pe_ & 0xFFFF0000u);                          \
        uint4 kv = *(const uint4*)(KV + (size_t)s_ * 256 + sub * 16);            \
        float2v k01 = __builtin_amdgcn_cvt_pk_f32_fp8(kv.x, false);              \
        float2v k23 = __builtin_amdgcn_cvt_pk_f32_fp8(kv.x, true);               \
        float2v k45 = __builtin_amdgcn_cvt_pk_f32_fp8(kv.y, false);              \
        float2v k67 = __builtin_amdgcn_cvt_pk_f32_fp8(kv.y, true);               \
        float p_ = k01[0] * q0;                                                  \
        p_ = fmaf(k01[1], q1, p_);                                               \
        p_ = fmaf(k23[0], q2, p_);                                               \
        p_ = fmaf(k23[1], q3, p_);                                               \
        p_ = fmaf(k45[0], q4, p_);                                               \
        p_ = fmaf(k45[1], q5, p_);                                               \
        p_ = fmaf(k67[0], q6, p_);                                               \
        p_ = fmaf(k67[1], q7, p_);                                               \
        p_ += __shfl_xor(p_, 1, 64);                                             \
        p_ += __shfl_xor(p_, 2, 64);                                             \
        float x0 = p_ * fmaf(ef_, uva.x, cva.x);                                 \
        float x1 = p_ * fmaf(ef_, uva.y, cva.y);                                 \
        float x2 = p_ * fmaf(ef_, uva.z, cva.z);                                 \
        float x3 = p_ * fmaf(ef_, uva.w, cva.w);                                 \
        float x4 = p_ * fmaf(ef_, uvb.x, cvb.x);                                 \
        float x5 = p_ * fmaf(ef_, uvb.y, cvb.y);                                 \
        float x6 = p_ * fmaf(ef_, uvb.z, cvb.z);                                 \
        float x7 = p_ * fmaf(ef_, uvb.w, cvb.w);                                 \
        if (MASKED) {                                                            \
            x0 = (VALID) ? x0 : -1.0e38f; x1 = (VALID) ? x1 : -1.0e38f;          \
            x2 = (VALID) ? x2 : -1.0e38f; x3 = (VALID) ? x3 : -1.0e38f;          \
            x4 = (VALID) ? x4 : -1.0e38f; x5 = (VALID) ? x5 : -1.0e38f;          \
            x6 = (VALID) ? x6 : -1.0e38f; x7 = (VALID) ? x7 : -1.0e38f;          \
        }                                                                        \
        float xm = fmaxf(fmaxf(fmaxf(x0, x1), fmaxf(x2, x3)),                    \
                         fmaxf(fmaxf(x4, x5), fmaxf(x6, x7)));                   \
        if (xm > m) {                                                            \
            float nm = xm + 6.0f;                                                \
            float sc = EXP2(m - nm);                                             \
            sA[0] *= sc; sA[1] *= sc; sA[2] *= sc; sA[3] *= sc;                  \
            sA[4] *= sc; sA[5] *= sc; sA[6] *= sc; sA[7] *= sc;                  \
            o[0] *= sc; o[1] *= sc; o[2] *= sc; o[3] *= sc;                      \
            o[4] *= sc; o[5] *= sc; o[6] *= sc; o[7] *= sc;                      \
            m = nm;                                                              \
        }                                                                        \
        float e0 = EXP2(x0 - m), e1 = EXP2(x1 - m);                              \
        float e2 = EXP2(x2 - m), e3 = EXP2(x3 - m);                              \
        float e4 = EXP2(x4 - m), e5 = EXP2(x5 - m);                              \
        float e6 = EXP2(x6 - m), e7 = EXP2(x7 - m);                              \
        sA[0] += e0; sA[1] += e1; sA[2] += e2; sA[3] += e3;                      \
        sA[4] += e4; sA[5] += e5; sA[6] += e6; sA[7] += e7;                      \
        float2v v01 = __builtin_amdgcn_cvt_pk_f32_fp8(kv.z, false);              \
        float2v v23 = __builtin_amdgcn_cvt_pk_f32_fp8(kv.z, true);               \
        float2v v45 = __builtin_amdgcn_cvt_pk_f32_fp8(kv.w, false);              \
        float2v v67 = __builtin_amdgcn_cvt_pk_f32_fp8(kv.w, true);               \
        o[0] = fmaf(v01[0], e0, o[0]);                                           \
        o[1] = fmaf(v01[1], e1, o[1]);                                           \
        o[2] = fmaf(v23[0], e2, o[2]);                                           \
        o[3] = fmaf(v23[1], e3, o[3]);                                           \
        o[4] = fmaf(v45[0], e4, o[4]);                                           \
        o[5] = fmaf(v45[1], e5, o[5]);                                           \
        o[6] = fmaf(v67[0], e6, o[6]);                                           \
        o[7] = fmaf(v67[1], e7, o[7]);                                           \
    }

    for (int it = 0; it < nfull; ++it, ep += 4) {
        AGG_BODY(*ep, false, true)
    }
    const int rem = deg & 3;
    if (rem) {
        bool valid = grp < rem;
        unsigned int pe = valid ? *ep : edges[start];
        AGG_BODY(pe, true, valid)
    }
#undef AGG_BODY

    // merge the 4 edge-groups (partners lane^16, lane^32 hold the same dims)
#pragma unroll
    for (int mask = 16; mask <= 32; mask <<= 1) {
        float mo = __shfl_xor(m, mask, 64);
        float mm = fmaxf(m, mo);
        float sca = EXP2(m - mm);
        float scb = EXP2(mo - mm);
#pragma unroll
        for (int j = 0; j < 8; ++j) {
            float t = __shfl_xor(sA[j], mask, 64);
            sA[j] = sA[j] * sca + t * scb;
            t = __shfl_xor(o[j], mask, 64);
            o[j] = o[j] * sca + t * scb;
        }
        m = mm;
    }

    if (grp == 0) {
        // ref: h_out = num / max(Z, 1e-6); ours scaled by 2^m; 1e-37 NaN guard
        float zc = 1e-6f * EXP2(-m);
        uint4 ou;
        unsigned int w0, w1;
        float z;
        z = fmaxf(fmaxf(sA[0], zc), 1e-37f); w0 = f2bf(o[0] / z);
        z = fmaxf(fmaxf(sA[1], zc), 1e-37f); w1 = f2bf(o[1] / z);
        ou.x = w0 | (w1 << 16);
        z = fmaxf(fmaxf(sA[2], zc), 1e-37f); w0 = f2bf(o[2] / z);
        z = fmaxf(fmaxf(sA[3], zc), 1e-37f); w1 = f2bf(o[3] / z);
        ou.y = w0 | (w1 << 16);
        z = fmaxf(fmaxf(sA[4], zc), 1e-37f); w0 = f2bf(o[4] / z);
        z = fmaxf(fmaxf(sA[5], zc), 1e-37f); w1 = f2bf(o[5] / z);
        ou.z = w0 | (w1 << 16);
        z = fmaxf(fmaxf(sA[6], zc), 1e-37f); w0 = f2bf(o[6] / z);
        z = fmaxf(fmaxf(sA[7], zc), 1e-37f); w1 = f2bf(o[7] / z);
        ou.w = w0 | (w1 << 16);
        *(uint4*)(hout + (size_t)v * 128 + sub * 8) = ou;
    }
}

// ---------------- mean over nodes ------------------------------------------------------
__global__ void mean_part_kernel(const float* __restrict__ h, float* __restrict__ macc) {
    __shared__ float s[256];
    int t = threadIdx.x;
    int col = t & 127;
    int half = t >> 7;
    int r0 = blockIdx.x * 256;
    float acc = 0.f;
    for (int r = half; r < 256; r += 2) acc += h[(size_t)(r0 + r) * 128 + col];
    s[t] = acc;
    __syncthreads();
    if (t < 128) atomicAdd(&macc[t], s[t] + s[t + 128]);
}

__global__ void finalize_kernel(const float* __restrict__ macc, void* __restrict__ out,
                                const int* __restrict__ flag) {
    int t = threadIdx.x;
    float v = macc[t] * (1.f / (float)N_NODES);
    if (*flag)
        ((ushort_t*)out)[t] = f2bf(v);
    else
        ((float*)out)[t] = v;
}

// ---------------------------------------------------------------------------------------
extern "C" void kernel_launch(void* const* d_in, const int* in_sizes, int n_in,
                              void* d_out, int out_size, void* d_ws, size_t ws_size,
                              hipStream_t stream) {
    const int* src = (const int*)d_in[3];
    const int* dst = (const int*)d_in[4];

    char* w = (char*)d_ws;
    const size_t MB = 1u << 20;
    float* h        = (float*)(w);               // 16 MB [N,128] f32
    ushort_t* hb    = (ushort_t*)(w + 16 * MB);  //  8 MB [N,128] bf16 (also = HOUT)
    ushort_t* Qh    = (ushort_t*)(w + 24 * MB);  //  8 MB [N,128] bf16
    unsigned char* KVf8 = (unsigned char*)(w + 32 * MB);  // 8 MB [N,256B] fp8 K|V packed
    char* aux       = w + 48 * MB;
    int* deg        = (int*)(aux);               // 128 KB
    int* rowstart   = (int*)(aux + 0x40000);     // 128 KB + 4
    int* cursor     = (int*)(aux + 0x80000);     // 128 KB
    unsigned int* edges = (unsigned int*)(aux + 0xC0000);          // 2 MB
    float* ubuf     = (float*)(aux + 0xC0000 + 2 * MB);            // 3*128 f32
    float* cbuf     = ubuf + 3 * 128;
    float* macc     = cbuf + 3 * 128;            // 128 f32
    int* flag       = (int*)(macc + 128);
    float* conv     = (float*)(aux + 0xC0000 + 2 * MB + 4096);     // 1.73 MB f32
    ushort_t* swz   = (ushort_t*)((char*)conv + CONV_TOTAL * 4);   // 768 KB bf16
    // total ≈ 53.2 MB

    hipMemsetAsync(deg, 0, N_NODES * sizeof(int), stream);
    hipMemsetAsync(macc, 0, 128 * sizeof(float), stream);

    detect_kernel<<<1, 256, 0, stream>>>((const unsigned int*)d_in[5], flag);

    ConvArgs ca;
    ca.src[0] = d_in[5];   ca.src[1] = d_in[6];   ca.src[2] = d_in[7];
    ca.src[3] = d_in[8];   ca.src[4] = d_in[9];   ca.src[5] = d_in[10];
    ca.src[6] = d_in[11];  ca.src[7] = d_in[12];  ca.src[8] = d_in[13];
    ca.src[9] = d_in[14];  ca.src[10] = d_in[15]; ca.src[11] = d_in[16];
    ca.src[12] = d_in[17]; ca.src[13] = d_in[18]; ca.src[14] = d_in[19];
    ca.src[15] = d_in[20]; ca.src[16] = d_in[21]; ca.src[17] = d_in[22];
    ca.src[18] = d_in[23]; ca.src[19] = d_in[24];
    convert_kernel<<<(CONV_TOTAL + 255) / 256, 256, 0, stream>>>(ca, flag, conv);
    swz_kernel<<<REC_TOTAL * 64 / 256, 256, 0, stream>>>(conv, swz);

    input_proj_kernel<<<N_NODES * 32 / 256, 256, 0, stream>>>(d_in[0], d_in[1], conv,
                                                              flag, h, hb);
    uc_kernel<<<3, 128, 0, stream>>>(conv, ubuf, cbuf);
    hist_kernel<<<N_EDGES / 256, 256, 0, stream>>>(dst, deg);
    scan_kernel<<<1, 1024, 0, stream>>>(deg, rowstart, cursor);
    scatter_kernel<<<N_EDGES / 256, 256, 0, stream>>>(src, dst, d_in[2], flag, cursor,
                                                      edges);

    for (int i = 0; i < 3; ++i) {
        const ushort_t* swzQKV = swz + (size_t)REC_QKV(i) * 512;
        const ushort_t* swzWL  = swz + (size_t)REC_WLIN(i) * 512;
        const ushort_t* swzF1  = swz + (size_t)REC_WF1(i) * 512;
        const ushort_t* swzF2  = swz + (size_t)REC_WF2(i) * 512;

        // Q bf16 + K/V fp8 packed — one wave per 16 rows, all 384 cols, coalesced
        qkv_kernel<<<N_NODES / 16, 64, 0, stream>>>(hb, swzQKV, Qh, KVf8);

        // attention -> hb (= HOUT) [N,128] bf16
        agg_kernel<<<N_NODES, 64, 0, stream>>>(Qh, KVf8, rowstart, edges,
                                               ubuf + i * 128, cbuf + i * 128, hb);

        // fused layer tail, one wave per 16 rows (grid 2048)
        ffn_kernel<<<N_NODES / 16, 64, 0, stream>>>(
            hb, swzWL, swzF1, swzF2,
            conv + OFF_BLIN + i * 128, conv + OFF_G1 + i * 128, conv + OFF_BE1 + i * 128,
            conv + OFF_BF1 + i * 256,
            conv + OFF_BF2 + i * 128, conv + OFF_G2 + i * 128, conv + OFF_BE2 + i * 128,
            h, hb);
    }

    mean_part_kernel<<<N_NODES / 256, 256, 0, stream>>>(h, macc);
    finalize_kernel<<<1, 128, 0, stream>>>(macc, d_out, flag);
}

// Round 15
// 508.682 us; speedup vs baseline: 1.0706x; 1.0706x over previous
//
#include <hip/hip_runtime.h>
#include <hip/hip_bf16.h>

#define N_NODES 32768
#define N_EDGES 524288
#define LN_EPS 1e-5f

typedef unsigned short ushort_t;
typedef __attribute__((ext_vector_type(8))) short short8v;
typedef __attribute__((ext_vector_type(4))) float float4v;
typedef __attribute__((ext_vector_type(2))) float float2v;

__device__ __forceinline__ float bf2f(ushort_t u) {
    return __uint_as_float(((unsigned int)u) << 16);
}
__device__ __forceinline__ ushort_t f2bf(float f) {
    unsigned int u = __float_as_uint(f);
    unsigned int r = (u + 0x7FFFu + ((u >> 16) & 1u)) >> 16;
    return (ushort_t)r;
}
__device__ __forceinline__ float lo16(unsigned int x) { return __uint_as_float(x << 16); }
__device__ __forceinline__ float hi16(unsigned int x) { return __uint_as_float(x & 0xFFFF0000u); }

#if __has_builtin(__builtin_amdgcn_exp2f)
#define EXP2(x) __builtin_amdgcn_exp2f(x)
#else
#define EXP2(x) exp2f(x)
#endif

// conv-region element offsets (f32 scratch holding all weight tensors)
#define OFF_WNODE 0
#define OFF_BNODE 5632
#define OFF_WPOS  5760
#define OFF_BPOS  6784
#define OFF_WEDGE 6912
#define OFF_BEDGE 7040
#define OFF_WQ    7168
#define OFF_WK    56320
#define OFF_WV    105472
#define OFF_WE    154624
#define OFF_WLIN  203776
#define OFF_BLIN  252928
#define OFF_G1    253312
#define OFF_BE1   253696
#define OFF_WF1   254080
#define OFF_BF1   352384
#define OFF_WF2   353152
#define OFF_BF2   451456
#define OFF_G2    451840
#define OFF_BE2   452224
#define CONV_TOTAL 452608

// swizzled-B record bases (records of 512 ushorts = 64 lanes x 8 bf16)
#define REC_QKV(i)  ((i) * 96)          // 24 ct x 4 kb
#define REC_WLIN(i) (288 + (i) * 32)    // 8 ct x 4 kb
#define REC_WF1(i)  (384 + (i) * 64)    // 16 ct x 4 kb
#define REC_WF2(i)  (576 + (i) * 64)    // 8 ct x 8 kb
#define REC_TOTAL   768

#define LDS_STRIDE 264   // ushorts per LDS row (256 + 8 pad)
#define LDS_FSTRIDE 132  // floats per LDS row (same byte footprint)

// ---------------- dtype detection: bf16 data has exponent-like bits at [15:8] ---------
__global__ void detect_kernel(const unsigned int* __restrict__ wn, int* __restrict__ flag) {
    __shared__ int s[256];
    int t = threadIdx.x;
    int cnt = 0;
    for (int i = t; i < 2816; i += 256) {
        unsigned int b = (wn[i] >> 8) & 0x7F;
        cnt += (b >= 0x3A && b <= 0x40) ? 1 : 0;
    }
    s[t] = cnt;
    __syncthreads();
    for (int off = 128; off > 0; off >>= 1) {
        if (t < off) s[t] += s[t + off];
        __syncthreads();
    }
    if (t == 0) *flag = (s[0] > 1408) ? 1 : 0;   // 1 = bf16, 0 = f32
}

// ---------------- canonicalize all weight buffers to f32 scratch ----------------------
struct ConvArgs { const void* src[20]; };

__global__ void convert_kernel(ConvArgs a, const int* __restrict__ flag,
                               float* __restrict__ dst) {
    int gid = blockIdx.x * 256 + threadIdx.x;
    if (gid >= CONV_TOTAL) return;
    const int off[21] = {OFF_WNODE, OFF_BNODE, OFF_WPOS, OFF_BPOS, OFF_WEDGE, OFF_BEDGE,
                         OFF_WQ, OFF_WK, OFF_WV, OFF_WE, OFF_WLIN, OFF_BLIN, OFF_G1,
                         OFF_BE1, OFF_WF1, OFF_BF1, OFF_WF2, OFF_BF2, OFF_G2, OFF_BE2,
                         CONV_TOTAL};
    int s = 0;
#pragma unroll
    for (int i = 1; i < 20; ++i) s += (gid >= off[i]) ? 1 : 0;
    int local = gid - off[s];
    if (*flag)
        dst[gid] = bf2f(((const ushort_t*)a.src[s])[local]);
    else
        dst[gid] = ((const float*)a.src[s])[local];
}

// ---------------- swizzle GEMM weights into MFMA B-fragment records -------------------
// record(ct,kb): lane l holds W[kb*32 + (l>>4)*8 + j][ct*16 + (l&15)], j=0..7
__global__ void swz_kernel(const float* __restrict__ conv, ushort_t* __restrict__ swz) {
    int gid = blockIdx.x * 256 + threadIdx.x;   // REC_TOTAL*64 threads
    int lane = gid & 63;
    int rec = gid >> 6;
    if (rec >= REC_TOTAL) return;
    int col = lane & 15, quad = lane >> 4;
    const float* src;
    int ct, kb, OC;
    if (rec < 288) {                       // QKV: 3 layers x 24ct x 4kb
        int layer = rec / 96, r2 = rec % 96;
        ct = r2 >> 2; kb = r2 & 3;
        int seg = ct >> 3;                 // 0=Wq 1=Wk 2=Wv
        int base = (seg == 0 ? OFF_WQ : (seg == 1 ? OFF_WK : OFF_WV)) + layer * 16384;
        src = conv + base; OC = 128; ct &= 7;
    } else if (rec < 384) {                // W_lin
        int r = rec - 288, layer = r / 32, r2 = r % 32;
        ct = r2 >> 2; kb = r2 & 3;
        src = conv + OFF_WLIN + layer * 16384; OC = 128;
    } else if (rec < 576) {                // Wf1 (OC=256)
        int r = rec - 384, layer = r / 64, r2 = r % 64;
        ct = r2 >> 2; kb = r2 & 3;
        src = conv + OFF_WF1 + layer * 32768; OC = 256;
    } else {                               // Wf2 (K=256)
        int r = rec - 576, layer = r / 64, r2 = r % 64;
        ct = r2 >> 3; kb = r2 & 7;
        src = conv + OFF_WF2 + layer * 32768; OC = 128;
    }
    int n = ct * 16 + col;
    ushort_t v[8];
#pragma unroll
    for (int j = 0; j < 8; ++j) v[j] = f2bf(src[(size_t)(kb * 32 + quad * 8 + j) * OC + n]);
    ushort_t* o = swz + (size_t)rec * 512 + lane * 8;
#pragma unroll
    for (int j = 0; j < 8; ++j) o[j] = v[j];
}

// ---------------- input projection -> h f32 + hb bf16 ---------------------------------
__global__ void input_proj_kernel(const void* __restrict__ feats,
                                  const void* __restrict__ lap,
                                  const float* __restrict__ conv,
                                  const int* __restrict__ flag,
                                  float* __restrict__ h, ushort_t* __restrict__ hb) {
    int gid = blockIdx.x * 256 + threadIdx.x;   // N*32 threads
    int node = gid >> 5;
    int cg = (gid & 31) * 4;
    bool isbf = (*flag != 0);
    const float* Wn = conv + OFF_WNODE;
    const float* Wp = conv + OFF_WPOS;

    float4 b1 = *(const float4*)(conv + OFF_BNODE + cg);
    float4 b2 = *(const float4*)(conv + OFF_BPOS + cg);
    float a0 = b1.x + b2.x, a1 = b1.y + b2.y, a2 = b1.z + b2.z, a3 = b1.w + b2.w;

#define ACC(fv, Wbase, kk)                                            \
    {                                                                 \
        float4 wv_ = *(const float4*)(Wbase + (size_t)(kk) * 128 + cg); \
        a0 = fmaf(fv, wv_.x, a0);                                     \
        a1 = fmaf(fv, wv_.y, a1);                                     \
        a2 = fmaf(fv, wv_.z, a2);                                     \
        a3 = fmaf(fv, wv_.w, a3);                                     \
    }

    if (isbf) {
        const ushort_t* frow = (const ushort_t*)feats + (size_t)node * 44;
        const ushort_t* prow = (const ushort_t*)lap + (size_t)node * 8;
#pragma unroll
        for (int i = 0; i < 11; ++i) {
            ushort4 f = *(const ushort4*)(frow + i * 4);
            ACC(bf2f(f.x), Wn, i * 4 + 0)
            ACC(bf2f(f.y), Wn, i * 4 + 1)
            ACC(bf2f(f.z), Wn, i * 4 + 2)
            ACC(bf2f(f.w), Wn, i * 4 + 3)
        }
#pragma unroll
        for (int i = 0; i < 2; ++i) {
            ushort4 f = *(const ushort4*)(prow + i * 4);
            ACC(bf2f(f.x), Wp, i * 4 + 0)
            ACC(bf2f(f.y), Wp, i * 4 + 1)
            ACC(bf2f(f.z), Wp, i * 4 + 2)
            ACC(bf2f(f.w), Wp, i * 4 + 3)
        }
    } else {
        const float4* frow = (const float4*)((const float*)feats + (size_t)node * 44);
        const float4* prow = (const float4*)((const float*)lap + (size_t)node * 8);
#pragma unroll
        for (int i = 0; i < 11; ++i) {
            float4 f = frow[i];
            ACC(f.x, Wn, i * 4 + 0)
            ACC(f.y, Wn, i * 4 + 1)
            ACC(f.z, Wn, i * 4 + 2)
            ACC(f.w, Wn, i * 4 + 3)
        }
#pragma unroll
        for (int i = 0; i < 2; ++i) {
            float4 f = prow[i];
            ACC(f.x, Wp, i * 4 + 0)
            ACC(f.y, Wp, i * 4 + 1)
            ACC(f.z, Wp, i * 4 + 2)
            ACC(f.w, Wp, i * 4 + 3)
        }
    }
#undef ACC

    size_t idx = (size_t)node * 128 + cg;
    *(float4*)(h + idx) = make_float4(a0, a1, a2, a3);
    ushort4 ob;
    ob.x = f2bf(a0); ob.y = f2bf(a1); ob.z = f2bf(a2); ob.w = f2bf(a3);
    *(ushort4*)(hb + idx) = ob;
}

// ---------------- u_l, c1_l for the collapsed edge GEMM -------------------------------
// Pre-scaled by (1/sqrt(dk))*log2(e): agg works in the log2 domain with raw v_exp.
__global__ void uc_kernel(const float* __restrict__ conv,
                          float* __restrict__ u, float* __restrict__ c1) {
    int l = blockIdx.x;
    int d = threadIdx.x;
    const float* W_edge = conv + OFF_WEDGE;
    const float* b_edge = conv + OFF_BEDGE;
    const float* Wl = conv + OFF_WE + l * 128 * 128;
    float uu = 0.f, cc = 0.f;
#pragma unroll 4
    for (int k = 0; k < 128; ++k) {
        float w = Wl[k * 128 + d];
        uu += W_edge[k] * w;
        cc += b_edge[k] * w;
    }
    const float scale = 0.17677669529663687f * 1.4426950408889634f;  // isq * log2(e)
    u[l * 128 + d] = uu * scale;
    c1[l * 128 + d] = (1.f + cc) * scale;
}

// ---------------- CSR build ------------------------------------------------------------
__global__ void hist_kernel(const int* __restrict__ dst, int* __restrict__ deg) {
    int e = blockIdx.x * 256 + threadIdx.x;
    if (e < N_EDGES) atomicAdd(&deg[dst[e]], 1);
}

__global__ void scan_kernel(const int* __restrict__ deg, int* __restrict__ rowstart,
                            int* __restrict__ cursor) {
    __shared__ int lds[1024];
    int t = threadIdx.x;
    int base = t * 32;
    int v[32];
    int csum = 0;
#pragma unroll
    for (int j = 0; j < 32; ++j) { v[j] = deg[base + j]; csum += v[j]; }
    lds[t] = csum;
    __syncthreads();
    for (int off = 1; off < 1024; off <<= 1) {
        int x = (t >= off) ? lds[t - off] : 0;
        __syncthreads();
        lds[t] += x;
        __syncthreads();
    }
    int excl = lds[t] - csum;
    int running = excl;
#pragma unroll
    for (int j = 0; j < 32; ++j) {
        rowstart[base + j] = running;
        cursor[base + j] = running;
        running += v[j];
    }
    if (t == 1023) rowstart[N_NODES] = running;
}

__global__ void scatter_kernel(const int* __restrict__ src, const int* __restrict__ dst,
                               const void* __restrict__ ef, const int* __restrict__ flag,
                               int* __restrict__ cursor,
                               unsigned int* __restrict__ edges) {
    int e = blockIdx.x * 256 + threadIdx.x;
    if (e < N_EDGES) {
        ushort_t efb = (*flag != 0) ? ((const ushort_t*)ef)[e]
                                    : f2bf(((const float*)ef)[e]);
        int d = dst[e];
        int p = atomicAdd(&cursor[d], 1);
        edges[p] = (unsigned int)src[e] | ((unsigned int)efb << 16);
    }
}

// ---------------- MFMA GEMM (QKV): seg 0 -> Q bf16 [N,128];
//                  segs 1/2 -> K/V packed fp8-e4m3 into KV [N,256B]
//                  (per 8-dim block b: bytes 16b..16b+7 = K dims, +8..+15 = V dims).
// Block: 256 thr = 4 waves; wave = 16 rows x 128 cols; grid = (M/64, 3 segs).
template <int KB>
__global__ __launch_bounds__(256) void qkv_gemm(
    const ushort_t* __restrict__ A,
    const ushort_t* __restrict__ Bswz,
    ushort_t* __restrict__ outQ,
    unsigned char* __restrict__ outKV) {
    const int K = KB * 32;
    const int tid = threadIdx.x;
    const int wv = tid >> 6, lane = tid & 63;
    const int col = lane & 15, quad = lane >> 4;
    const int m0 = blockIdx.x * 64 + wv * 16;
    const int ct0 = blockIdx.y * 8;

    float4v acc[8];
#pragma unroll
    for (int ct = 0; ct < 8; ++ct) acc[ct] = (float4v){0.f, 0.f, 0.f, 0.f};

    const ushort_t* Ap = A + (size_t)(m0 + col) * K + quad * 8;
    const ushort_t* Bp = Bswz + (size_t)ct0 * KB * 512 + lane * 8;

#pragma unroll
    for (int kb = 0; kb < KB; ++kb) {
        short8v a = *(const short8v*)(Ap + kb * 32);
#pragma unroll
        for (int ct = 0; ct < 8; ++ct) {
            short8v b = *(const short8v*)(Bp + (size_t)(ct * KB + kb) * 512);
            acc[ct] = __builtin_amdgcn_mfma_f32_16x16x32_bf16(a, b, acc[ct], 0, 0, 0);
        }
    }

    const int rowb = m0 + quad * 4;
    const int seg = blockIdx.y;
    if (seg == 0) {
#pragma unroll
        for (int ct = 0; ct < 8; ++ct) {
            int j = ct * 16 + col;
#pragma unroll
            for (int r = 0; r < 4; ++r)
                outQ[(size_t)(rowb + r) * 128 + j] = f2bf(acc[ct][r]);
        }
    } else {
        const int vofs = (seg == 2) ? 8 : 0;
#pragma unroll
        for (int ct = 0; ct < 8; ++ct) {
            int j = ct * 16 + col;
            int off = ((j >> 3) * 16) + (j & 7) + vofs;
#pragma unroll
            for (int r = 0; r < 4; ++r) {
                float a = acc[ct][r];
                float b = __shfl_xor(a, 1, 64);   // partner col (j^1) same ct,r
                if ((col & 1) == 0) {
                    unsigned short pk = (unsigned short)
                        __builtin_amdgcn_cvt_pk_fp8_f32(a, b, 0, false);
                    *(ushort_t*)(outKV + (size_t)(rowb + r) * 256 + off) = pk;
                }
            }
        }
    }
}

// ---------------- fused layer tail: h = LN2(h' + relu(h'@Wf1+b)@Wf2+b2),
//                  h' = LN1(h + HOUT@WL+bl). One wave per 16 rows (grid N/16).
__global__ __launch_bounds__(64, 2) void ffn_kernel(
    const ushort_t* __restrict__ HOUT,   // [N,128] bf16 (= hb, attention out)
    const ushort_t* __restrict__ BWL,    // swz W_lin  (8ct x 4kb)
    const ushort_t* __restrict__ BF1,    // swz Wf1    (16ct x 4kb)
    const ushort_t* __restrict__ BF2,    // swz Wf2    (8ct x 8kb)
    const float* __restrict__ bl,
    const float* __restrict__ g1v, const float* __restrict__ be1v,
    const float* __restrict__ bf1v,
    const float* __restrict__ bf2v,
    const float* __restrict__ g2v, const float* __restrict__ be2v,
    float* __restrict__ h,               // [N,128] f32 in-out (residual -> final)
    ushort_t* __restrict__ hb) {         // [N,128] bf16 out
    __shared__ __align__(16) char ldsraw[16 * 528];   // 8448 B, dual-view
    ushort_t* ldsu = (ushort_t*)ldsraw;  // stride LDS_STRIDE (264)
    float* ldsf = (float*)ldsraw;        // stride LDS_FSTRIDE (132)
    const int lane = threadIdx.x & 63;
    const int col = lane & 15, quad = lane >> 4;
    const int m0 = blockIdx.x * 16;
    const int rowb = m0 + quad * 4;          // global row base (C-layout)
    const int lrowc = quad * 4;              // LDS row base for C-layout stores
    const int lrowa = col;                   // LDS row for A-fragment reads

    // ---- GEMM1: HOUT @ W_lin ----
    float4v acc[8];
#pragma unroll
    for (int ct = 0; ct < 8; ++ct) acc[ct] = (float4v){0.f, 0.f, 0.f, 0.f};
    const ushort_t* Ap = HOUT + (size_t)(m0 + col) * 128 + quad * 8;
#pragma unroll
    for (int kb = 0; kb < 4; ++kb) {
        short8v a = *(const short8v*)(Ap + kb * 32);
#pragma unroll
        for (int ct = 0; ct < 8; ++ct) {
            short8v b = *(const short8v*)(BWL + (size_t)(ct * 4 + kb) * 512 + lane * 8);
            acc[ct] = __builtin_amdgcn_mfma_f32_16x16x32_bf16(a, b, acc[ct], 0, 0, 0);
        }
    }

    // ---- LN1 (+bias, +residual h) -> val (h', kept in registers) ----
    float val[8][4], s[4] = {0.f, 0.f, 0.f, 0.f}, ss[4] = {0.f, 0.f, 0.f, 0.f};
#pragma unroll
    for (int ct = 0; ct < 8; ++ct) {
        float bi = bl[ct * 16 + col];
#pragma unroll
        for (int r = 0; r < 4; ++r) {
            float v = acc[ct][r] + bi + h[(size_t)(rowb + r) * 128 + ct * 16 + col];
            val[ct][r] = v;
            s[r] += v;
            ss[r] += v * v;
        }
    }
#pragma unroll
    for (int mask = 1; mask < 16; mask <<= 1) {
#pragma unroll
        for (int r = 0; r < 4; ++r) {
            s[r] += __shfl_xor(s[r], mask, 64);
            ss[r] += __shfl_xor(ss[r], mask, 64);
        }
    }
#pragma unroll
    for (int r = 0; r < 4; ++r) {
        float mean = s[r] * (1.f / 128.f);
        float var = ss[r] * (1.f / 128.f) - mean * mean;
        s[r] = mean;
        ss[r] = rsqrtf(var + LN_EPS);
    }
#pragma unroll
    for (int ct = 0; ct < 8; ++ct) {
        float gg = g1v[ct * 16 + col], bb = be1v[ct * 16 + col];
#pragma unroll
        for (int r = 0; r < 4; ++r) {
            float o = (val[ct][r] - s[r]) * ss[r] * gg + bb;
            val[ct][r] = o;                                      // residual for LN2
            ldsu[(lrowc + r) * LDS_STRIDE + ct * 16 + col] = f2bf(o);
        }
    }
    __syncthreads();

    // ---- A-fragments of h' from LDS ----
    short8v af[4];
#pragma unroll
    for (int kb = 0; kb < 4; ++kb)
        af[kb] = *(const short8v*)&ldsu[lrowa * LDS_STRIDE + kb * 32 + quad * 8];

    // ---- GEMM2: h' @ Wf1 (OC=256) ----
    float4v acc2[16];
#pragma unroll
    for (int ct = 0; ct < 16; ++ct) acc2[ct] = (float4v){0.f, 0.f, 0.f, 0.f};
#pragma unroll
    for (int kb = 0; kb < 4; ++kb) {
#pragma unroll
        for (int ct = 0; ct < 16; ++ct) {
            short8v b = *(const short8v*)(BF1 + (size_t)(ct * 4 + kb) * 512 + lane * 8);
            acc2[ct] = __builtin_amdgcn_mfma_f32_16x16x32_bf16(af[kb], b, acc2[ct], 0, 0, 0);
        }
    }
    __syncthreads();

    // ---- T = relu(acc2 + bf1) -> LDS ----
#pragma unroll
    for (int ct = 0; ct < 16; ++ct) {
        float bi = bf1v[ct * 16 + col];
#pragma unroll
        for (int r = 0; r < 4; ++r) {
            float v = fmaxf(acc2[ct][r] + bi, 0.f);
            ldsu[(lrowc + r) * LDS_STRIDE + ct * 16 + col] = f2bf(v);
        }
    }
    __syncthreads();

    // ---- GEMM3: T @ Wf2 (K=256) ----
    float4v acc3[8];
#pragma unroll
    for (int ct = 0; ct < 8; ++ct) acc3[ct] = (float4v){0.f, 0.f, 0.f, 0.f};
#pragma unroll
    for (int kb = 0; kb < 8; ++kb) {
        short8v a = *(const short8v*)&ldsu[lrowa * LDS_STRIDE + kb * 32 + quad * 8];
#pragma unroll
        for (int ct = 0; ct < 8; ++ct) {
            short8v b = *(const short8v*)(BF2 + (size_t)(ct * 8 + kb) * 512 + lane * 8);
            acc3[ct] = __builtin_amdgcn_mfma_f32_16x16x32_bf16(a, b, acc3[ct], 0, 0, 0);
        }
    }

    // ---- LN2 (+bias, +residual h') ----
    float s2[4] = {0.f, 0.f, 0.f, 0.f}, ss2[4] = {0.f, 0.f, 0.f, 0.f};
#pragma unroll
    for (int ct = 0; ct < 8; ++ct) {
        float bi = bf2v[ct * 16 + col];
#pragma unroll
        for (int r = 0; r < 4; ++r) {
            float v = acc3[ct][r] + bi + val[ct][r];
            val[ct][r] = v;
            s2[r] += v;
            ss2[r] += v * v;
        }
    }
#pragma unroll
    for (int mask = 1; mask < 16; mask <<= 1) {
#pragma unroll
        for (int r = 0; r < 4; ++r) {
            s2[r] += __shfl_xor(s2[r], mask, 64);
            ss2[r] += __shfl_xor(ss2[r], mask, 64);
        }
    }
#pragma unroll
    for (int r = 0; r < 4; ++r) {
        float mean = s2[r] * (1.f / 128.f);
        float var = ss2[r] * (1.f / 128.f) - mean * mean;
        s2[r] = mean;
        ss2[r] = rsqrtf(var + LN_EPS);
    }
    __syncthreads();   // T fully consumed; reuse LDS as f32 staging
#pragma unroll
    for (int ct = 0; ct < 8; ++ct) {
        float gg = g2v[ct * 16 + col], bb = be2v[ct * 16 + col];
#pragma unroll
        for (int r = 0; r < 4; ++r) {
            float o = (val[ct][r] - s2[r]) * ss2[r] * gg + bb;
            ldsf[(lrowc + r) * LDS_FSTRIDE + ct * 16 + col] = o;
        }
    }
    __syncthreads();

    // ---- coalesced stores: h as float4, hb as uint4 (8 bf16) ----
#pragma unroll
    for (int j = 0; j < 8; ++j) {
        int p = lane + j * 64;        // 0..511
        int row = p >> 5;
        int c4 = p & 31;
        float4 vv = *(const float4*)&ldsf[row * LDS_FSTRIDE + c4 * 4];
        *(float4*)&h[(size_t)(m0 + row) * 128 + c4 * 4] = vv;
    }
#pragma unroll
    for (int j = 0; j < 4; ++j) {
        int p = lane + j * 64;        // 0..255
        int row = p >> 4;
        int c8 = p & 15;
        float4 va = *(const float4*)&ldsf[row * LDS_FSTRIDE + c8 * 8];
        float4 vb = *(const float4*)&ldsf[row * LDS_FSTRIDE + c8 * 8 + 4];
        uint4 ou;
        ou.x = (unsigned)f2bf(va.x) | ((unsigned)f2bf(va.y) << 16);
        ou.y = (unsigned)f2bf(va.z) | ((unsigned)f2bf(va.w) << 16);
        ou.z = (unsigned)f2bf(vb.x) | ((unsigned)f2bf(vb.y) << 16);
        ou.w = (unsigned)f2bf(vb.z) | ((unsigned)f2bf(vb.w) << 16);
        *(uint4*)&hb[(size_t)(m0 + row) * 128 + c8 * 8] = ou;
    }
}

// ---------------- attention aggregation --------------------------------------------
// One WAVE per dst node. 4 edge-groups x 16 lanes; lane covers 8 dims (sub = lane&15).
// Q bf16 [N,128]; K/V fp8-e4m3 packed [N,256B] -> ONE uint4 gather per edge per lane.
// Log2-domain lazy-max online softmax (u/c1 pre-scaled by isq*log2e).
__global__ __launch_bounds__(64) void agg_kernel(
    const ushort_t* __restrict__ Q, const unsigned char* __restrict__ KV,
    const int* __restrict__ rowstart, const unsigned int* __restrict__ edges,
    const float* __restrict__ u, const float* __restrict__ c1,
    ushort_t* __restrict__ hout) {
    const int lane = threadIdx.x & 63;
    const int v = blockIdx.x;
    const int sub = lane & 15;
    const int grp = lane >> 4;

    // Q dims 8sub..+7 (uint4 = 8 bf16)
    uint4 qu = *(const uint4*)(Q + (size_t)v * 128 + sub * 8);
    float q0 = lo16(qu.x), q1 = hi16(qu.x), q2 = lo16(qu.y), q3 = hi16(qu.y);
    float q4 = lo16(qu.z), q5 = hi16(qu.z), q6 = lo16(qu.w), q7 = hi16(qu.w);
    float4 uva = *(const float4*)(u + sub * 8);
    float4 uvb = *(const float4*)(u + sub * 8 + 4);
    float4 cva = *(const float4*)(c1 + sub * 8);
    float4 cvb = *(const float4*)(c1 + sub * 8 + 4);

    float m = -1.0e38f;
    float sA[8] = {0.f, 0.f, 0.f, 0.f, 0.f, 0.f, 0.f, 0.f};
    float o[8] = {0.f, 0.f, 0.f, 0.f, 0.f, 0.f, 0.f, 0.f};

    const int start = rowstart[v];
    const int deg = rowstart[v + 1] - start;
    const int nfull = deg >> 2;
    const unsigned int* ep = edges + start + grp;

#define AGG_BODY(PE, MASKED, VALID)                                              \
    {                                                                            \
        unsigned int pe_ = (PE);                                                 \
        int s_ = (int)(pe_ & 0xFFFFu);                                           \
        float ef_ = __uint_as_float(pe_ & 0xFFFF0000u);                          \
        uint4 kv = *(const uint4*)(KV + (size_t)s_ * 256 + sub * 16);            \
        float2v k01 = __builtin_amdgcn_cvt_pk_f32_fp8(kv.x, false);              \
        float2v k23 = __builtin_amdgcn_cvt_pk_f32_fp8(kv.x, true);               \
        float2v k45 = __builtin_amdgcn_cvt_pk_f32_fp8(kv.y, false);              \
        float2v k67 = __builtin_amdgcn_cvt_pk_f32_fp8(kv.y, true);               \
        float p_ = k01[0] * q0;                                                  \
        p_ = fmaf(k01[1], q1, p_);                                               \
        p_ = fmaf(k23[0], q2, p_);                                               \
        p_ = fmaf(k23[1], q3, p_);                                               \
        p_ = fmaf(k45[0], q4, p_);                                               \
        p_ = fmaf(k45[1], q5, p_);                                               \
        p_ = fmaf(k67[0], q6, p_);                                               \
        p_ = fmaf(k67[1], q7, p_);                                               \
        p_ += __shfl_xor(p_, 1, 64);                                             \
        p_ += __shfl_xor(p_, 2, 64);                                             \
        float x0 = p_ * fmaf(ef_, uva.x, cva.x);                                 \
        float x1 = p_ * fmaf(ef_, uva.y, cva.y);                                 \
        float x2 = p_ * fmaf(ef_, uva.z, cva.z);                                 \
        float x3 = p_ * fmaf(ef_, uva.w, cva.w);                                 \
        float x4 = p_ * fmaf(ef_, uvb.x, cvb.x);                                 \
        float x5 = p_ * fmaf(ef_, uvb.y, cvb.y);                                 \
        float x6 = p_ * fmaf(ef_, uvb.z, cvb.z);                                 \
        float x7 = p_ * fmaf(ef_, uvb.w, cvb.w);                                 \
        if (MASKED) {                                                            \
            x0 = (VALID) ? x0 : -1.0e38f; x1 = (VALID) ? x1 : -1.0e38f;          \
            x2 = (VALID) ? x2 : -1.0e38f; x3 = (VALID) ? x3 : -1.0e38f;          \
            x4 = (VALID) ? x4 : -1.0e38f; x5 = (VALID) ? x5 : -1.0e38f;          \
            x6 = (VALID) ? x6 : -1.0e38f; x7 = (VALID) ? x7 : -1.0e38f;          \
        }                                                                        \
        float xm = fmaxf(fmaxf(fmaxf(x0, x1), fmaxf(x2, x3)),                    \
                         fmaxf(fmaxf(x4, x5), fmaxf(x6, x7)));                   \
        if (xm > m) {                                                            \
            float nm = xm + 6.0f;                                                \
            float sc = EXP2(m - nm);                                             \
            sA[0] *= sc; sA[1] *= sc; sA[2] *= sc; sA[3] *= sc;                  \
            sA[4] *= sc; sA[5] *= sc; sA[6] *= sc; sA[7] *= sc;                  \
            o[0] *= sc; o[1] *= sc; o[2] *= sc; o[3] *= sc;                      \
            o[4] *= sc; o[5] *= sc; o[6] *= sc; o[7] *= sc;                      \
            m = nm;                                                              \
        }                                                                        \
        float e0 = EXP2(x0 - m), e1 = EXP2(x1 - m);                              \
        float e2 = EXP2(x2 - m), e3 = EXP2(x3 - m);                              \
        float e4 = EXP2(x4 - m), e5 = EXP2(x5 - m);                              \
        float e6 = EXP2(x6 - m), e7 = EXP2(x7 - m);                              \
        sA[0] += e0; sA[1] += e1; sA[2] += e2; sA[3] += e3;                      \
        sA[4] += e4; sA[5] += e5; sA[6] += e6; sA[7] += e7;                      \
        float2v v01 = __builtin_amdgcn_cvt_pk_f32_fp8(kv.z, false);              \
        float2v v23 = __builtin_amdgcn_cvt_pk_f32_fp8(kv.z, true);               \
        float2v v45 = __builtin_amdgcn_cvt_pk_f32_fp8(kv.w, false);              \
        float2v v67 = __builtin_amdgcn_cvt_pk_f32_fp8(kv.w, true);               \
        o[0] = fmaf(v01[0], e0, o[0]);                                           \
        o[1] = fmaf(v01[1], e1, o[1]);                                           \
        o[2] = fmaf(v23[0], e2, o[2]);                                           \
        o[3] = fmaf(v23[1], e3, o[3]);                                           \
        o[4] = fmaf(v45[0], e4, o[4]);                                           \
        o[5] = fmaf(v45[1], e5, o[5]);                                           \
        o[6] = fmaf(v67[0], e6, o[6]);                                           \
        o[7] = fmaf(v67[1], e7, o[7]);                                           \
    }

    for (int it = 0; it < nfull; ++it, ep += 4) {
        AGG_BODY(*ep, false, true)
    }
    const int rem = deg & 3;
    if (rem) {
        bool valid = grp < rem;
        unsigned int pe = valid ? *ep : edges[start];
        AGG_BODY(pe, true, valid)
    }
#undef AGG_BODY

    // merge the 4 edge-groups (partners lane^16, lane^32 hold the same dims)
#pragma unroll
    for (int mask = 16; mask <= 32; mask <<= 1) {
        float mo = __shfl_xor(m, mask, 64);
        float mm = fmaxf(m, mo);
        float sca = EXP2(m - mm);
        float scb = EXP2(mo - mm);
#pragma unroll
        for (int j = 0; j < 8; ++j) {
            float t = __shfl_xor(sA[j], mask, 64);
            sA[j] = sA[j] * sca + t * scb;
            t = __shfl_xor(o[j], mask, 64);
            o[j] = o[j] * sca + t * scb;
        }
        m = mm;
    }

    if (grp == 0) {
        // ref: h_out = num / max(Z, 1e-6); ours scaled by 2^m; 1e-37 NaN guard
        float zc = 1e-6f * EXP2(-m);
        uint4 ou;
        unsigned int w0, w1;
        float z;
        z = fmaxf(fmaxf(sA[0], zc), 1e-37f); w0 = f2bf(o[0] / z);
        z = fmaxf(fmaxf(sA[1], zc), 1e-37f); w1 = f2bf(o[1] / z);
        ou.x = w0 | (w1 << 16);
        z = fmaxf(fmaxf(sA[2], zc), 1e-37f); w0 = f2bf(o[2] / z);
        z = fmaxf(fmaxf(sA[3], zc), 1e-37f); w1 = f2bf(o[3] / z);
        ou.y = w0 | (w1 << 16);
        z = fmaxf(fmaxf(sA[4], zc), 1e-37f); w0 = f2bf(o[4] / z);
        z = fmaxf(fmaxf(sA[5], zc), 1e-37f); w1 = f2bf(o[5] / z);
        ou.z = w0 | (w1 << 16);
        z = fmaxf(fmaxf(sA[6], zc), 1e-37f); w0 = f2bf(o[6] / z);
        z = fmaxf(fmaxf(sA[7], zc), 1e-37f); w1 = f2bf(o[7] / z);
        ou.w = w0 | (w1 << 16);
        *(uint4*)(hout + (size_t)v * 128 + sub * 8) = ou;
    }
}

// ---------------- mean over nodes ------------------------------------------------------
__global__ void mean_part_kernel(const float* __restrict__ h, float* __restrict__ macc) {
    __shared__ float s[256];
    int t = threadIdx.x;
    int col = t & 127;
    int half = t >> 7;
    int r0 = blockIdx.x * 256;
    float acc = 0.f;
    for (int r = half; r < 256; r += 2) acc += h[(size_t)(r0 + r) * 128 + col];
    s[t] = acc;
    __syncthreads();
    if (t < 128) atomicAdd(&macc[t], s[t] + s[t + 128]);
}

__global__ void finalize_kernel(const float* __restrict__ macc, void* __restrict__ out,
                                const int* __restrict__ flag) {
    int t = threadIdx.x;
    float v = macc[t] * (1.f / (float)N_NODES);
    if (*flag)
        ((ushort_t*)out)[t] = f2bf(v);
    else
        ((float*)out)[t] = v;
}

// ---------------------------------------------------------------------------------------
extern "C" void kernel_launch(void* const* d_in, const int* in_sizes, int n_in,
                              void* d_out, int out_size, void* d_ws, size_t ws_size,
                              hipStream_t stream) {
    const int* src = (const int*)d_in[3];
    const int* dst = (const int*)d_in[4];

    char* w = (char*)d_ws;
    const size_t MB = 1u << 20;
    float* h        = (float*)(w);               // 16 MB [N,128] f32
    ushort_t* hb    = (ushort_t*)(w + 16 * MB);  //  8 MB [N,128] bf16 (also = HOUT)
    ushort_t* Qh    = (ushort_t*)(w + 24 * MB);  //  8 MB [N,128] bf16
    unsigned char* KVf8 = (unsigned char*)(w + 32 * MB);  // 8 MB [N,256B] fp8 K|V packed
    char* aux       = w + 48 * MB;
    int* deg        = (int*)(aux);               // 128 KB
    int* rowstart   = (int*)(aux + 0x40000);     // 128 KB + 4
    int* cursor     = (int*)(aux + 0x80000);     // 128 KB
    unsigned int* edges = (unsigned int*)(aux + 0xC0000);          // 2 MB
    float* ubuf     = (float*)(aux + 0xC0000 + 2 * MB);            // 3*128 f32
    float* cbuf     = ubuf + 3 * 128;
    float* macc     = cbuf + 3 * 128;            // 128 f32
    int* flag       = (int*)(macc + 128);
    float* conv     = (float*)(aux + 0xC0000 + 2 * MB + 4096);     // 1.73 MB f32
    ushort_t* swz   = (ushort_t*)((char*)conv + CONV_TOTAL * 4);   // 768 KB bf16
    // total ≈ 53.2 MB

    hipMemsetAsync(deg, 0, N_NODES * sizeof(int), stream);
    hipMemsetAsync(macc, 0, 128 * sizeof(float), stream);

    detect_kernel<<<1, 256, 0, stream>>>((const unsigned int*)d_in[5], flag);

    ConvArgs ca;
    ca.src[0] = d_in[5];   ca.src[1] = d_in[6];   ca.src[2] = d_in[7];
    ca.src[3] = d_in[8];   ca.src[4] = d_in[9];   ca.src[5] = d_in[10];
    ca.src[6] = d_in[11];  ca.src[7] = d_in[12];  ca.src[8] = d_in[13];
    ca.src[9] = d_in[14];  ca.src[10] = d_in[15]; ca.src[11] = d_in[16];
    ca.src[12] = d_in[17]; ca.src[13] = d_in[18]; ca.src[14] = d_in[19];
    ca.src[15] = d_in[20]; ca.src[16] = d_in[21]; ca.src[17] = d_in[22];
    ca.src[18] = d_in[23]; ca.src[19] = d_in[24];
    convert_kernel<<<(CONV_TOTAL + 255) / 256, 256, 0, stream>>>(ca, flag, conv);
    swz_kernel<<<REC_TOTAL * 64 / 256, 256, 0, stream>>>(conv, swz);

    input_proj_kernel<<<N_NODES * 32 / 256, 256, 0, stream>>>(d_in[0], d_in[1], conv,
                                                              flag, h, hb);
    uc_kernel<<<3, 128, 0, stream>>>(conv, ubuf, cbuf);
    hist_kernel<<<N_EDGES / 256, 256, 0, stream>>>(dst, deg);
    scan_kernel<<<1, 1024, 0, stream>>>(deg, rowstart, cursor);
    scatter_kernel<<<N_EDGES / 256, 256, 0, stream>>>(src, dst, d_in[2], flag, cursor,
                                                      edges);

    for (int i = 0; i < 3; ++i) {
        const ushort_t* swzQKV = swz + (size_t)REC_QKV(i) * 512;
        const ushort_t* swzWL  = swz + (size_t)REC_WLIN(i) * 512;
        const ushort_t* swzF1  = swz + (size_t)REC_WF1(i) * 512;
        const ushort_t* swzF2  = swz + (size_t)REC_WF2(i) * 512;

        // Q bf16 + K/V fp8 packed (3-segment, 4-wave blocks — R13 config)
        qkv_gemm<4><<<dim3(N_NODES / 64, 3), 256, 0, stream>>>(hb, swzQKV, Qh, KVf8);

        // attention -> hb (= HOUT) [N,128] bf16
        agg_kernel<<<N_NODES, 64, 0, stream>>>(Qh, KVf8, rowstart, edges,
                                               ubuf + i * 128, cbuf + i * 128, hb);

        // fused layer tail, one wave per 16 rows (grid 2048)
        ffn_kernel<<<N_NODES / 16, 64, 0, stream>>>(
            hb, swzWL, swzF1, swzF2,
            conv + OFF_BLIN + i * 128, conv + OFF_G1 + i * 128, conv + OFF_BE1 + i * 128,
            conv + OFF_BF1 + i * 256,
            conv + OFF_BF2 + i * 128, conv + OFF_G2 + i * 128, conv + OFF_BE2 + i * 128,
            h, hb);
    }

    mean_part_kernel<<<N_NODES / 256, 256, 0, stream>>>(h, macc);
    finalize_kernel<<<1, 128, 0, stream>>>(macc, d_out, flag);
}

// Round 16
// 505.002 us; speedup vs baseline: 1.0784x; 1.0073x over previous
//
#include <hip/hip_runtime.h>
#include <hip/hip_bf16.h>

#define N_NODES 32768
#define N_EDGES 524288
#define LN_EPS 1e-5f

typedef unsigned short ushort_t;
typedef __attribute__((ext_vector_type(8))) short short8v;
typedef __attribute__((ext_vector_type(4))) float float4v;
typedef __attribute__((ext_vector_type(2))) float float2v;

__device__ __forceinline__ float bf2f(ushort_t u) {
    return __uint_as_float(((unsigned int)u) << 16);
}
__device__ __forceinline__ ushort_t f2bf(float f) {
    unsigned int u = __float_as_uint(f);
    unsigned int r = (u + 0x7FFFu + ((u >> 16) & 1u)) >> 16;
    return (ushort_t)r;
}
__device__ __forceinline__ float lo16(unsigned int x) { return __uint_as_float(x << 16); }
__device__ __forceinline__ float hi16(unsigned int x) { return __uint_as_float(x & 0xFFFF0000u); }

#if __has_builtin(__builtin_amdgcn_exp2f)
#define EXP2(x) __builtin_amdgcn_exp2f(x)
#else
#define EXP2(x) exp2f(x)
#endif

// conv-region element offsets (f32 scratch holding all weight tensors)
#define OFF_WNODE 0
#define OFF_BNODE 5632
#define OFF_WPOS  5760
#define OFF_BPOS  6784
#define OFF_WEDGE 6912
#define OFF_BEDGE 7040
#define OFF_WQ    7168
#define OFF_WK    56320
#define OFF_WV    105472
#define OFF_WE    154624
#define OFF_WLIN  203776
#define OFF_BLIN  252928
#define OFF_G1    253312
#define OFF_BE1   253696
#define OFF_WF1   254080
#define OFF_BF1   352384
#define OFF_WF2   353152
#define OFF_BF2   451456
#define OFF_G2    451840
#define OFF_BE2   452224
#define CONV_TOTAL 452608

// swizzled-B record bases (records of 512 ushorts = 64 lanes x 8 bf16)
#define REC_QKV(i)  ((i) * 96)          // 24 ct x 4 kb
#define REC_WLIN(i) (288 + (i) * 32)    // 8 ct x 4 kb
#define REC_WF1(i)  (384 + (i) * 64)    // 16 ct x 4 kb
#define REC_WF2(i)  (576 + (i) * 64)    // 8 ct x 8 kb
#define REC_TOTAL   768

#define LDS_STRIDE 264   // ushorts per LDS row (256 + 8 pad)
#define LDS_FSTRIDE 132  // floats per LDS row (same byte footprint)

// ---------------- dtype detection: bf16 data has exponent-like bits at [15:8] ---------
__global__ void detect_kernel(const unsigned int* __restrict__ wn, int* __restrict__ flag) {
    __shared__ int s[256];
    int t = threadIdx.x;
    int cnt = 0;
    for (int i = t; i < 2816; i += 256) {
        unsigned int b = (wn[i] >> 8) & 0x7F;
        cnt += (b >= 0x3A && b <= 0x40) ? 1 : 0;
    }
    s[t] = cnt;
    __syncthreads();
    for (int off = 128; off > 0; off >>= 1) {
        if (t < off) s[t] += s[t + off];
        __syncthreads();
    }
    if (t == 0) *flag = (s[0] > 1408) ? 1 : 0;   // 1 = bf16, 0 = f32
}

// ---------------- canonicalize all weight buffers to f32 scratch ----------------------
struct ConvArgs { const void* src[20]; };

__global__ void convert_kernel(ConvArgs a, const int* __restrict__ flag,
                               float* __restrict__ dst) {
    int gid = blockIdx.x * 256 + threadIdx.x;
    if (gid >= CONV_TOTAL) return;
    const int off[21] = {OFF_WNODE, OFF_BNODE, OFF_WPOS, OFF_BPOS, OFF_WEDGE, OFF_BEDGE,
                         OFF_WQ, OFF_WK, OFF_WV, OFF_WE, OFF_WLIN, OFF_BLIN, OFF_G1,
                         OFF_BE1, OFF_WF1, OFF_BF1, OFF_WF2, OFF_BF2, OFF_G2, OFF_BE2,
                         CONV_TOTAL};
    int s = 0;
#pragma unroll
    for (int i = 1; i < 20; ++i) s += (gid >= off[i]) ? 1 : 0;
    int local = gid - off[s];
    if (*flag)
        dst[gid] = bf2f(((const ushort_t*)a.src[s])[local]);
    else
        dst[gid] = ((const float*)a.src[s])[local];
}

// ---------------- swizzle GEMM weights into MFMA B-fragment records -------------------
// record(ct,kb): lane l holds W[kb*32 + (l>>4)*8 + j][ct*16 + (l&15)], j=0..7
__global__ void swz_kernel(const float* __restrict__ conv, ushort_t* __restrict__ swz) {
    int gid = blockIdx.x * 256 + threadIdx.x;   // REC_TOTAL*64 threads
    int lane = gid & 63;
    int rec = gid >> 6;
    if (rec >= REC_TOTAL) return;
    int col = lane & 15, quad = lane >> 4;
    const float* src;
    int ct, kb, OC;
    if (rec < 288) {                       // QKV: 3 layers x 24ct x 4kb
        int layer = rec / 96, r2 = rec % 96;
        ct = r2 >> 2; kb = r2 & 3;
        int seg = ct >> 3;                 // 0=Wq 1=Wk 2=Wv
        int base = (seg == 0 ? OFF_WQ : (seg == 1 ? OFF_WK : OFF_WV)) + layer * 16384;
        src = conv + base; OC = 128; ct &= 7;
    } else if (rec < 384) {                // W_lin
        int r = rec - 288, layer = r / 32, r2 = r % 32;
        ct = r2 >> 2; kb = r2 & 3;
        src = conv + OFF_WLIN + layer * 16384; OC = 128;
    } else if (rec < 576) {                // Wf1 (OC=256)
        int r = rec - 384, layer = r / 64, r2 = r % 64;
        ct = r2 >> 2; kb = r2 & 3;
        src = conv + OFF_WF1 + layer * 32768; OC = 256;
    } else {                               // Wf2 (K=256)
        int r = rec - 576, layer = r / 64, r2 = r % 64;
        ct = r2 >> 3; kb = r2 & 7;
        src = conv + OFF_WF2 + layer * 32768; OC = 128;
    }
    int n = ct * 16 + col;
    ushort_t v[8];
#pragma unroll
    for (int j = 0; j < 8; ++j) v[j] = f2bf(src[(size_t)(kb * 32 + quad * 8 + j) * OC + n]);
    ushort_t* o = swz + (size_t)rec * 512 + lane * 8;
#pragma unroll
    for (int j = 0; j < 8; ++j) o[j] = v[j];
}

// ---------------- input projection -> h f32 + hb bf16 ---------------------------------
__global__ void input_proj_kernel(const void* __restrict__ feats,
                                  const void* __restrict__ lap,
                                  const float* __restrict__ conv,
                                  const int* __restrict__ flag,
                                  float* __restrict__ h, ushort_t* __restrict__ hb) {
    int gid = blockIdx.x * 256 + threadIdx.x;   // N*32 threads
    int node = gid >> 5;
    int cg = (gid & 31) * 4;
    bool isbf = (*flag != 0);
    const float* Wn = conv + OFF_WNODE;
    const float* Wp = conv + OFF_WPOS;

    float4 b1 = *(const float4*)(conv + OFF_BNODE + cg);
    float4 b2 = *(const float4*)(conv + OFF_BPOS + cg);
    float a0 = b1.x + b2.x, a1 = b1.y + b2.y, a2 = b1.z + b2.z, a3 = b1.w + b2.w;

#define ACC(fv, Wbase, kk)                                            \
    {                                                                 \
        float4 wv_ = *(const float4*)(Wbase + (size_t)(kk) * 128 + cg); \
        a0 = fmaf(fv, wv_.x, a0);                                     \
        a1 = fmaf(fv, wv_.y, a1);                                     \
        a2 = fmaf(fv, wv_.z, a2);                                     \
        a3 = fmaf(fv, wv_.w, a3);                                     \
    }

    if (isbf) {
        const ushort_t* frow = (const ushort_t*)feats + (size_t)node * 44;
        const ushort_t* prow = (const ushort_t*)lap + (size_t)node * 8;
#pragma unroll
        for (int i = 0; i < 11; ++i) {
            ushort4 f = *(const ushort4*)(frow + i * 4);
            ACC(bf2f(f.x), Wn, i * 4 + 0)
            ACC(bf2f(f.y), Wn, i * 4 + 1)
            ACC(bf2f(f.z), Wn, i * 4 + 2)
            ACC(bf2f(f.w), Wn, i * 4 + 3)
        }
#pragma unroll
        for (int i = 0; i < 2; ++i) {
            ushort4 f = *(const ushort4*)(prow + i * 4);
            ACC(bf2f(f.x), Wp, i * 4 + 0)
            ACC(bf2f(f.y), Wp, i * 4 + 1)
            ACC(bf2f(f.z), Wp, i * 4 + 2)
            ACC(bf2f(f.w), Wp, i * 4 + 3)
        }
    } else {
        const float4* frow = (const float4*)((const float*)feats + (size_t)node * 44);
        const float4* prow = (const float4*)((const float*)lap + (size_t)node * 8);
#pragma unroll
        for (int i = 0; i < 11; ++i) {
            float4 f = frow[i];
            ACC(f.x, Wn, i * 4 + 0)
            ACC(f.y, Wn, i * 4 + 1)
            ACC(f.z, Wn, i * 4 + 2)
            ACC(f.w, Wn, i * 4 + 3)
        }
#pragma unroll
        for (int i = 0; i < 2; ++i) {
            float4 f = prow[i];
            ACC(f.x, Wp, i * 4 + 0)
            ACC(f.y, Wp, i * 4 + 1)
            ACC(f.z, Wp, i * 4 + 2)
            ACC(f.w, Wp, i * 4 + 3)
        }
    }
#undef ACC

    size_t idx = (size_t)node * 128 + cg;
    *(float4*)(h + idx) = make_float4(a0, a1, a2, a3);
    ushort4 ob;
    ob.x = f2bf(a0); ob.y = f2bf(a1); ob.z = f2bf(a2); ob.w = f2bf(a3);
    *(ushort4*)(hb + idx) = ob;
}

// ---------------- u_l, c1_l for the collapsed edge GEMM -------------------------------
// Pre-scaled by (1/sqrt(dk))*log2(e): agg works in the log2 domain with raw v_exp.
__global__ void uc_kernel(const float* __restrict__ conv,
                          float* __restrict__ u, float* __restrict__ c1) {
    int l = blockIdx.x;
    int d = threadIdx.x;
    const float* W_edge = conv + OFF_WEDGE;
    const float* b_edge = conv + OFF_BEDGE;
    const float* Wl = conv + OFF_WE + l * 128 * 128;
    float uu = 0.f, cc = 0.f;
#pragma unroll 4
    for (int k = 0; k < 128; ++k) {
        float w = Wl[k * 128 + d];
        uu += W_edge[k] * w;
        cc += b_edge[k] * w;
    }
    const float scale = 0.17677669529663687f * 1.4426950408889634f;  // isq * log2(e)
    u[l * 128 + d] = uu * scale;
    c1[l * 128 + d] = (1.f + cc) * scale;
}

// ---------------- CSR build ------------------------------------------------------------
__global__ void hist_kernel(const int* __restrict__ dst, int* __restrict__ deg) {
    int e = blockIdx.x * 256 + threadIdx.x;
    if (e < N_EDGES) atomicAdd(&deg[dst[e]], 1);
}

__global__ void scan_kernel(const int* __restrict__ deg, int* __restrict__ rowstart,
                            int* __restrict__ cursor) {
    __shared__ int lds[1024];
    int t = threadIdx.x;
    int base = t * 32;
    int v[32];
    int csum = 0;
#pragma unroll
    for (int j = 0; j < 32; ++j) { v[j] = deg[base + j]; csum += v[j]; }
    lds[t] = csum;
    __syncthreads();
    for (int off = 1; off < 1024; off <<= 1) {
        int x = (t >= off) ? lds[t - off] : 0;
        __syncthreads();
        lds[t] += x;
        __syncthreads();
    }
    int excl = lds[t] - csum;
    int running = excl;
#pragma unroll
    for (int j = 0; j < 32; ++j) {
        rowstart[base + j] = running;
        cursor[base + j] = running;
        running += v[j];
    }
    if (t == 1023) rowstart[N_NODES] = running;
}

__global__ void scatter_kernel(const int* __restrict__ src, const int* __restrict__ dst,
                               const void* __restrict__ ef, const int* __restrict__ flag,
                               int* __restrict__ cursor,
                               unsigned int* __restrict__ edges) {
    int e = blockIdx.x * 256 + threadIdx.x;
    if (e < N_EDGES) {
        ushort_t efb = (*flag != 0) ? ((const ushort_t*)ef)[e]
                                    : f2bf(((const float*)ef)[e]);
        int d = dst[e];
        int p = atomicAdd(&cursor[d], 1);
        edges[p] = (unsigned int)src[e] | ((unsigned int)efb << 16);
    }
}

// ---------------- MFMA GEMM (QKV): seg 0 -> Q bf16 [N,128];
//                  segs 1/2 -> K/V packed fp8-e4m3 into KV [N,256B]
//                  (per 8-dim block b: bytes 16b..16b+7 = K dims, +8..+15 = V dims).
// Block: 256 thr = 4 waves; wave = 16 rows x 128 cols; grid = (M/64, 3 segs).
template <int KB>
__global__ __launch_bounds__(256) void qkv_gemm(
    const ushort_t* __restrict__ A,
    const ushort_t* __restrict__ Bswz,
    ushort_t* __restrict__ outQ,
    unsigned char* __restrict__ outKV) {
    const int K = KB * 32;
    const int tid = threadIdx.x;
    const int wv = tid >> 6, lane = tid & 63;
    const int col = lane & 15, quad = lane >> 4;
    const int m0 = blockIdx.x * 64 + wv * 16;
    const int ct0 = blockIdx.y * 8;

    float4v acc[8];
#pragma unroll
    for (int ct = 0; ct < 8; ++ct) acc[ct] = (float4v){0.f, 0.f, 0.f, 0.f};

    const ushort_t* Ap = A + (size_t)(m0 + col) * K + quad * 8;
    const ushort_t* Bp = Bswz + (size_t)ct0 * KB * 512 + lane * 8;

#pragma unroll
    for (int kb = 0; kb < KB; ++kb) {
        short8v a = *(const short8v*)(Ap + kb * 32);
#pragma unroll
        for (int ct = 0; ct < 8; ++ct) {
            short8v b = *(const short8v*)(Bp + (size_t)(ct * KB + kb) * 512);
            acc[ct] = __builtin_amdgcn_mfma_f32_16x16x32_bf16(a, b, acc[ct], 0, 0, 0);
        }
    }

    const int rowb = m0 + quad * 4;
    const int seg = blockIdx.y;
    if (seg == 0) {
#pragma unroll
        for (int ct = 0; ct < 8; ++ct) {
            int j = ct * 16 + col;
#pragma unroll
            for (int r = 0; r < 4; ++r)
                outQ[(size_t)(rowb + r) * 128 + j] = f2bf(acc[ct][r]);
        }
    } else {
        const int vofs = (seg == 2) ? 8 : 0;
#pragma unroll
        for (int ct = 0; ct < 8; ++ct) {
            int j = ct * 16 + col;
            int off = ((j >> 3) * 16) + (j & 7) + vofs;
#pragma unroll
            for (int r = 0; r < 4; ++r) {
                float a = acc[ct][r];
                float b = __shfl_xor(a, 1, 64);   // partner col (j^1) same ct,r
                if ((col & 1) == 0) {
                    unsigned short pk = (unsigned short)
                        __builtin_amdgcn_cvt_pk_fp8_f32(a, b, 0, false);
                    *(ushort_t*)(outKV + (size_t)(rowb + r) * 256 + off) = pk;
                }
            }
        }
    }
}

// ---------------- fused layer tail: h = LN2(h' + relu(h'@Wf1+b)@Wf2+b2),
//                  h' = LN1(h + HOUT@WL+bl). One wave per 16 rows (grid N/16).
__global__ __launch_bounds__(64, 2) void ffn_kernel(
    const ushort_t* __restrict__ HOUT,   // [N,128] bf16 (= hb, attention out)
    const ushort_t* __restrict__ BWL,    // swz W_lin  (8ct x 4kb)
    const ushort_t* __restrict__ BF1,    // swz Wf1    (16ct x 4kb)
    const ushort_t* __restrict__ BF2,    // swz Wf2    (8ct x 8kb)
    const float* __restrict__ bl,
    const float* __restrict__ g1v, const float* __restrict__ be1v,
    const float* __restrict__ bf1v,
    const float* __restrict__ bf2v,
    const float* __restrict__ g2v, const float* __restrict__ be2v,
    float* __restrict__ h,               // [N,128] f32 in-out (residual -> final)
    ushort_t* __restrict__ hb) {         // [N,128] bf16 out
    __shared__ __align__(16) char ldsraw[16 * 528];   // 8448 B, dual-view
    ushort_t* ldsu = (ushort_t*)ldsraw;  // stride LDS_STRIDE (264)
    float* ldsf = (float*)ldsraw;        // stride LDS_FSTRIDE (132)
    const int lane = threadIdx.x & 63;
    const int col = lane & 15, quad = lane >> 4;
    const int m0 = blockIdx.x * 16;
    const int rowb = m0 + quad * 4;          // global row base (C-layout)
    const int lrowc = quad * 4;              // LDS row base for C-layout stores
    const int lrowa = col;                   // LDS row for A-fragment reads

    // ---- GEMM1: HOUT @ W_lin ----
    float4v acc[8];
#pragma unroll
    for (int ct = 0; ct < 8; ++ct) acc[ct] = (float4v){0.f, 0.f, 0.f, 0.f};
    const ushort_t* Ap = HOUT + (size_t)(m0 + col) * 128 + quad * 8;
#pragma unroll
    for (int kb = 0; kb < 4; ++kb) {
        short8v a = *(const short8v*)(Ap + kb * 32);
#pragma unroll
        for (int ct = 0; ct < 8; ++ct) {
            short8v b = *(const short8v*)(BWL + (size_t)(ct * 4 + kb) * 512 + lane * 8);
            acc[ct] = __builtin_amdgcn_mfma_f32_16x16x32_bf16(a, b, acc[ct], 0, 0, 0);
        }
    }

    // ---- LN1 (+bias, +residual h) -> val (h', kept in registers) ----
    float val[8][4], s[4] = {0.f, 0.f, 0.f, 0.f}, ss[4] = {0.f, 0.f, 0.f, 0.f};
#pragma unroll
    for (int ct = 0; ct < 8; ++ct) {
        float bi = bl[ct * 16 + col];
#pragma unroll
        for (int r = 0; r < 4; ++r) {
            float v = acc[ct][r] + bi + h[(size_t)(rowb + r) * 128 + ct * 16 + col];
            val[ct][r] = v;
            s[r] += v;
            ss[r] += v * v;
        }
    }
#pragma unroll
    for (int mask = 1; mask < 16; mask <<= 1) {
#pragma unroll
        for (int r = 0; r < 4; ++r) {
            s[r] += __shfl_xor(s[r], mask, 64);
            ss[r] += __shfl_xor(ss[r], mask, 64);
        }
    }
#pragma unroll
    for (int r = 0; r < 4; ++r) {
        float mean = s[r] * (1.f / 128.f);
        float var = ss[r] * (1.f / 128.f) - mean * mean;
        s[r] = mean;
        ss[r] = rsqrtf(var + LN_EPS);
    }
#pragma unroll
    for (int ct = 0; ct < 8; ++ct) {
        float gg = g1v[ct * 16 + col], bb = be1v[ct * 16 + col];
#pragma unroll
        for (int r = 0; r < 4; ++r) {
            float o = (val[ct][r] - s[r]) * ss[r] * gg + bb;
            val[ct][r] = o;                                      // residual for LN2
            ldsu[(lrowc + r) * LDS_STRIDE + ct * 16 + col] = f2bf(o);
        }
    }
    __syncthreads();

    // ---- A-fragments of h' from LDS ----
    short8v af[4];
#pragma unroll
    for (int kb = 0; kb < 4; ++kb)
        af[kb] = *(const short8v*)&ldsu[lrowa * LDS_STRIDE + kb * 32 + quad * 8];

    // ---- GEMM2: h' @ Wf1 (OC=256) ----
    float4v acc2[16];
#pragma unroll
    for (int ct = 0; ct < 16; ++ct) acc2[ct] = (float4v){0.f, 0.f, 0.f, 0.f};
#pragma unroll
    for (int kb = 0; kb < 4; ++kb) {
#pragma unroll
        for (int ct = 0; ct < 16; ++ct) {
            short8v b = *(const short8v*)(BF1 + (size_t)(ct * 4 + kb) * 512 + lane * 8);
            acc2[ct] = __builtin_amdgcn_mfma_f32_16x16x32_bf16(af[kb], b, acc2[ct], 0, 0, 0);
        }
    }
    __syncthreads();

    // ---- T = relu(acc2 + bf1) -> LDS ----
#pragma unroll
    for (int ct = 0; ct < 16; ++ct) {
        float bi = bf1v[ct * 16 + col];
#pragma unroll
        for (int r = 0; r < 4; ++r) {
            float v = fmaxf(acc2[ct][r] + bi, 0.f);
            ldsu[(lrowc + r) * LDS_STRIDE + ct * 16 + col] = f2bf(v);
        }
    }
    __syncthreads();

    // ---- GEMM3: T @ Wf2 (K=256) ----
    float4v acc3[8];
#pragma unroll
    for (int ct = 0; ct < 8; ++ct) acc3[ct] = (float4v){0.f, 0.f, 0.f, 0.f};
#pragma unroll
    for (int kb = 0; kb < 8; ++kb) {
        short8v a = *(const short8v*)&ldsu[lrowa * LDS_STRIDE + kb * 32 + quad * 8];
#pragma unroll
        for (int ct = 0; ct < 8; ++ct) {
            short8v b = *(const short8v*)(BF2 + (size_t)(ct * 8 + kb) * 512 + lane * 8);
            acc3[ct] = __builtin_amdgcn_mfma_f32_16x16x32_bf16(a, b, acc3[ct], 0, 0, 0);
        }
    }

    // ---- LN2 (+bias, +residual h') ----
    float s2[4] = {0.f, 0.f, 0.f, 0.f}, ss2[4] = {0.f, 0.f, 0.f, 0.f};
#pragma unroll
    for (int ct = 0; ct < 8; ++ct) {
        float bi = bf2v[ct * 16 + col];
#pragma unroll
        for (int r = 0; r < 4; ++r) {
            float v = acc3[ct][r] + bi + val[ct][r];
            val[ct][r] = v;
            s2[r] += v;
            ss2[r] += v * v;
        }
    }
#pragma unroll
    for (int mask = 1; mask < 16; mask <<= 1) {
#pragma unroll
        for (int r = 0; r < 4; ++r) {
            s2[r] += __shfl_xor(s2[r], mask, 64);
            ss2[r] += __shfl_xor(ss2[r], mask, 64);
        }
    }
#pragma unroll
    for (int r = 0; r < 4; ++r) {
        float mean = s2[r] * (1.f / 128.f);
        float var = ss2[r] * (1.f / 128.f) - mean * mean;
        s2[r] = mean;
        ss2[r] = rsqrtf(var + LN_EPS);
    }
    __syncthreads();   // T fully consumed; reuse LDS as f32 staging
#pragma unroll
    for (int ct = 0; ct < 8; ++ct) {
        float gg = g2v[ct * 16 + col], bb = be2v[ct * 16 + col];
#pragma unroll
        for (int r = 0; r < 4; ++r) {
            float o = (val[ct][r] - s2[r]) * ss2[r] * gg + bb;
            ldsf[(lrowc + r) * LDS_FSTRIDE + ct * 16 + col] = o;
        }
    }
    __syncthreads();

    // ---- coalesced stores: h as float4, hb as uint4 (8 bf16) ----
#pragma unroll
    for (int j = 0; j < 8; ++j) {
        int p = lane + j * 64;        // 0..511
        int row = p >> 5;
        int c4 = p & 31;
        float4 vv = *(const float4*)&ldsf[row * LDS_FSTRIDE + c4 * 4];
        *(float4*)&h[(size_t)(m0 + row) * 128 + c4 * 4] = vv;
    }
#pragma unroll
    for (int j = 0; j < 4; ++j) {
        int p = lane + j * 64;        // 0..255
        int row = p >> 4;
        int c8 = p & 15;
        float4 va = *(const float4*)&ldsf[row * LDS_FSTRIDE + c8 * 8];
        float4 vb = *(const float4*)&ldsf[row * LDS_FSTRIDE + c8 * 8 + 4];
        uint4 ou;
        ou.x = (unsigned)f2bf(va.x) | ((unsigned)f2bf(va.y) << 16);
        ou.y = (unsigned)f2bf(va.z) | ((unsigned)f2bf(va.w) << 16);
        ou.z = (unsigned)f2bf(vb.x) | ((unsigned)f2bf(vb.y) << 16);
        ou.w = (unsigned)f2bf(vb.z) | ((unsigned)f2bf(vb.w) << 16);
        *(uint4*)&hb[(size_t)(m0 + row) * 128 + c8 * 8] = ou;
    }
}

// ---------------- attention aggregation --------------------------------------------
// One WAVE per dst node. 4 edge-groups x 16 lanes; lane covers 8 dims (sub = lane&15).
// Q bf16 [N,128]; K/V fp8-e4m3 packed [N,256B] -> ONE uint4 gather per edge per lane.
// Main loop UNROLLED x2 with BATCHED gathers: both KV loads issued before either
// compute body -> 2 outstanding gathers per wave during compute (R12's depth-1
// pipeline kept only 1 in flight; this doubles memory-level parallelism).
// Log2-domain lazy-max online softmax (u/c1 pre-scaled by isq*log2e).
__global__ __launch_bounds__(64) void agg_kernel(
    const ushort_t* __restrict__ Q, const unsigned char* __restrict__ KV,
    const int* __restrict__ rowstart, const unsigned int* __restrict__ edges,
    const float* __restrict__ u, const float* __restrict__ c1,
    ushort_t* __restrict__ hout) {
    const int lane = threadIdx.x & 63;
    const int v = blockIdx.x;
    const int sub = lane & 15;
    const int grp = lane >> 4;

    // Q dims 8sub..+7 (uint4 = 8 bf16)
    uint4 qu = *(const uint4*)(Q + (size_t)v * 128 + sub * 8);
    float q0 = lo16(qu.x), q1 = hi16(qu.x), q2 = lo16(qu.y), q3 = hi16(qu.y);
    float q4 = lo16(qu.z), q5 = hi16(qu.z), q6 = lo16(qu.w), q7 = hi16(qu.w);
    float4 uva = *(const float4*)(u + sub * 8);
    float4 uvb = *(const float4*)(u + sub * 8 + 4);
    float4 cva = *(const float4*)(c1 + sub * 8);
    float4 cvb = *(const float4*)(c1 + sub * 8 + 4);

    float m = -1.0e38f;
    float sA[8] = {0.f, 0.f, 0.f, 0.f, 0.f, 0.f, 0.f, 0.f};
    float o[8] = {0.f, 0.f, 0.f, 0.f, 0.f, 0.f, 0.f, 0.f};

    const int start = rowstart[v];
    const int deg = rowstart[v + 1] - start;
    const int nfull = deg >> 2;
    const unsigned int* ep = edges + start + grp;

// compute body consuming a pre-loaded edge word + KV vector
#define AGG_COMPUTE(PE, KVv, MASKED, VALID)                                      \
    {                                                                            \
        float ef_ = __uint_as_float((PE) & 0xFFFF0000u);                         \
        float2v k01 = __builtin_amdgcn_cvt_pk_f32_fp8((KVv).x, false);           \
        float2v k23 = __builtin_amdgcn_cvt_pk_f32_fp8((KVv).x, true);            \
        float2v k45 = __builtin_amdgcn_cvt_pk_f32_fp8((KVv).y, false);           \
        float2v k67 = __builtin_amdgcn_cvt_pk_f32_fp8((KVv).y, true);            \
        float p_ = k01[0] * q0;                                                  \
        p_ = fmaf(k01[1], q1, p_);                                               \
        p_ = fmaf(k23[0], q2, p_);                                               \
        p_ = fmaf(k23[1], q3, p_);                                               \
        p_ = fmaf(k45[0], q4, p_);                                               \
        p_ = fmaf(k45[1], q5, p_);                                               \
        p_ = fmaf(k67[0], q6, p_);                                               \
        p_ = fmaf(k67[1], q7, p_);                                               \
        p_ += __shfl_xor(p_, 1, 64);                                             \
        p_ += __shfl_xor(p_, 2, 64);                                             \
        float x0 = p_ * fmaf(ef_, uva.x, cva.x);                                 \
        float x1 = p_ * fmaf(ef_, uva.y, cva.y);                                 \
        float x2 = p_ * fmaf(ef_, uva.z, cva.z);                                 \
        float x3 = p_ * fmaf(ef_, uva.w, cva.w);                                 \
        float x4 = p_ * fmaf(ef_, uvb.x, cvb.x);                                 \
        float x5 = p_ * fmaf(ef_, uvb.y, cvb.y);                                 \
        float x6 = p_ * fmaf(ef_, uvb.z, cvb.z);                                 \
        float x7 = p_ * fmaf(ef_, uvb.w, cvb.w);                                 \
        if (MASKED) {                                                            \
            x0 = (VALID) ? x0 : -1.0e38f; x1 = (VALID) ? x1 : -1.0e38f;          \
            x2 = (VALID) ? x2 : -1.0e38f; x3 = (VALID) ? x3 : -1.0e38f;          \
            x4 = (VALID) ? x4 : -1.0e38f; x5 = (VALID) ? x5 : -1.0e38f;          \
            x6 = (VALID) ? x6 : -1.0e38f; x7 = (VALID) ? x7 : -1.0e38f;          \
        }                                                                        \
        float xm = fmaxf(fmaxf(fmaxf(x0, x1), fmaxf(x2, x3)),                    \
                         fmaxf(fmaxf(x4, x5), fmaxf(x6, x7)));                   \
        if (xm > m) {                                                            \
            float nm = xm + 6.0f;                                                \
            float sc = EXP2(m - nm);                                             \
            sA[0] *= sc; sA[1] *= sc; sA[2] *= sc; sA[3] *= sc;                  \
            sA[4] *= sc; sA[5] *= sc; sA[6] *= sc; sA[7] *= sc;                  \
            o[0] *= sc; o[1] *= sc; o[2] *= sc; o[3] *= sc;                      \
            o[4] *= sc; o[5] *= sc; o[6] *= sc; o[7] *= sc;                      \
            m = nm;                                                              \
        }                                                                        \
        float e0 = EXP2(x0 - m), e1 = EXP2(x1 - m);                              \
        float e2 = EXP2(x2 - m), e3 = EXP2(x3 - m);                              \
        float e4 = EXP2(x4 - m), e5 = EXP2(x5 - m);                              \
        float e6 = EXP2(x6 - m), e7 = EXP2(x7 - m);                              \
        sA[0] += e0; sA[1] += e1; sA[2] += e2; sA[3] += e3;                      \
        sA[4] += e4; sA[5] += e5; sA[6] += e6; sA[7] += e7;                      \
        float2v v01 = __builtin_amdgcn_cvt_pk_f32_fp8((KVv).z, false);           \
        float2v v23 = __builtin_amdgcn_cvt_pk_f32_fp8((KVv).z, true);            \
        float2v v45 = __builtin_amdgcn_cvt_pk_f32_fp8((KVv).w, false);           \
        float2v v67 = __builtin_amdgcn_cvt_pk_f32_fp8((KVv).w, true);            \
        o[0] = fmaf(v01[0], e0, o[0]);                                           \
        o[1] = fmaf(v01[1], e1, o[1]);                                           \
        o[2] = fmaf(v23[0], e2, o[2]);                                           \
        o[3] = fmaf(v23[1], e3, o[3]);                                           \
        o[4] = fmaf(v45[0], e4, o[4]);                                           \
        o[5] = fmaf(v45[1], e5, o[5]);                                           \
        o[6] = fmaf(v67[0], e6, o[6]);                                           \
        o[7] = fmaf(v67[1], e7, o[7]);                                           \
    }

    int it = 0;
    for (; it + 2 <= nfull; it += 2) {
        // batch: issue both edge words + both KV gathers before any compute
        unsigned int pe0 = ep[4 * it];
        unsigned int pe1 = ep[4 * it + 4];
        uint4 kv0 = *(const uint4*)(KV + (size_t)(pe0 & 0xFFFFu) * 256 + sub * 16);
        uint4 kv1 = *(const uint4*)(KV + (size_t)(pe1 & 0xFFFFu) * 256 + sub * 16);
        AGG_COMPUTE(pe0, kv0, false, true)
        AGG_COMPUTE(pe1, kv1, false, true)
    }
    if (it < nfull) {
        unsigned int pe0 = ep[4 * it];
        uint4 kv0 = *(const uint4*)(KV + (size_t)(pe0 & 0xFFFFu) * 256 + sub * 16);
        AGG_COMPUTE(pe0, kv0, false, true)
    }
    const int rem = deg & 3;
    if (rem) {
        bool valid = grp < rem;
        unsigned int pe = valid ? ep[4 * nfull] : edges[start];
        uint4 kv = *(const uint4*)(KV + (size_t)(pe & 0xFFFFu) * 256 + sub * 16);
        AGG_COMPUTE(pe, kv, true, valid)
    }
#undef AGG_COMPUTE

    // merge the 4 edge-groups (partners lane^16, lane^32 hold the same dims)
#pragma unroll
    for (int mask = 16; mask <= 32; mask <<= 1) {
        float mo = __shfl_xor(m, mask, 64);
        float mm = fmaxf(m, mo);
        float sca = EXP2(m - mm);
        float scb = EXP2(mo - mm);
#pragma unroll
        for (int j = 0; j < 8; ++j) {
            float t = __shfl_xor(sA[j], mask, 64);
            sA[j] = sA[j] * sca + t * scb;
            t = __shfl_xor(o[j], mask, 64);
            o[j] = o[j] * sca + t * scb;
        }
        m = mm;
    }

    if (grp == 0) {
        // ref: h_out = num / max(Z, 1e-6); ours scaled by 2^m; 1e-37 NaN guard
        float zc = 1e-6f * EXP2(-m);
        uint4 ou;
        unsigned int w0, w1;
        float z;
        z = fmaxf(fmaxf(sA[0], zc), 1e-37f); w0 = f2bf(o[0] / z);
        z = fmaxf(fmaxf(sA[1], zc), 1e-37f); w1 = f2bf(o[1] / z);
        ou.x = w0 | (w1 << 16);
        z = fmaxf(fmaxf(sA[2], zc), 1e-37f); w0 = f2bf(o[2] / z);
        z = fmaxf(fmaxf(sA[3], zc), 1e-37f); w1 = f2bf(o[3] / z);
        ou.y = w0 | (w1 << 16);
        z = fmaxf(fmaxf(sA[4], zc), 1e-37f); w0 = f2bf(o[4] / z);
        z = fmaxf(fmaxf(sA[5], zc), 1e-37f); w1 = f2bf(o[5] / z);
        ou.z = w0 | (w1 << 16);
        z = fmaxf(fmaxf(sA[6], zc), 1e-37f); w0 = f2bf(o[6] / z);
        z = fmaxf(fmaxf(sA[7], zc), 1e-37f); w1 = f2bf(o[7] / z);
        ou.w = w0 | (w1 << 16);
        *(uint4*)(hout + (size_t)v * 128 + sub * 8) = ou;
    }
}

// ---------------- mean over nodes ------------------------------------------------------
__global__ void mean_part_kernel(const float* __restrict__ h, float* __restrict__ macc) {
    __shared__ float s[256];
    int t = threadIdx.x;
    int col = t & 127;
    int half = t >> 7;
    int r0 = blockIdx.x * 256;
    float acc = 0.f;
    for (int r = half; r < 256; r += 2) acc += h[(size_t)(r0 + r) * 128 + col];
    s[t] = acc;
    __syncthreads();
    if (t < 128) atomicAdd(&macc[t], s[t] + s[t + 128]);
}

__global__ void finalize_kernel(const float* __restrict__ macc, void* __restrict__ out,
                                const int* __restrict__ flag) {
    int t = threadIdx.x;
    float v = macc[t] * (1.f / (float)N_NODES);
    if (*flag)
        ((ushort_t*)out)[t] = f2bf(v);
    else
        ((float*)out)[t] = v;
}

// ---------------------------------------------------------------------------------------
extern "C" void kernel_launch(void* const* d_in, const int* in_sizes, int n_in,
                              void* d_out, int out_size, void* d_ws, size_t ws_size,
                              hipStream_t stream) {
    const int* src = (const int*)d_in[3];
    const int* dst = (const int*)d_in[4];

    char* w = (char*)d_ws;
    const size_t MB = 1u << 20;
    float* h        = (float*)(w);               // 16 MB [N,128] f32
    ushort_t* hb    = (ushort_t*)(w + 16 * MB);  //  8 MB [N,128] bf16 (also = HOUT)
    ushort_t* Qh    = (ushort_t*)(w + 24 * MB);  //  8 MB [N,128] bf16
    unsigned char* KVf8 = (unsigned char*)(w + 32 * MB);  // 8 MB [N,256B] fp8 K|V packed
    char* aux       = w + 48 * MB;
    int* deg        = (int*)(aux);               // 128 KB
    int* rowstart   = (int*)(aux + 0x40000);     // 128 KB + 4
    int* cursor     = (int*)(aux + 0x80000);     // 128 KB
    unsigned int* edges = (unsigned int*)(aux + 0xC0000);          // 2 MB
    float* ubuf     = (float*)(aux + 0xC0000 + 2 * MB);            // 3*128 f32
    float* cbuf     = ubuf + 3 * 128;
    float* macc     = cbuf + 3 * 128;            // 128 f32
    int* flag       = (int*)(macc + 128);
    float* conv     = (float*)(aux + 0xC0000 + 2 * MB + 4096);     // 1.73 MB f32
    ushort_t* swz   = (ushort_t*)((char*)conv + CONV_TOTAL * 4);   // 768 KB bf16
    // total ≈ 53.2 MB

    hipMemsetAsync(deg, 0, N_NODES * sizeof(int), stream);
    hipMemsetAsync(macc, 0, 128 * sizeof(float), stream);

    detect_kernel<<<1, 256, 0, stream>>>((const unsigned int*)d_in[5], flag);

    ConvArgs ca;
    ca.src[0] = d_in[5];   ca.src[1] = d_in[6];   ca.src[2] = d_in[7];
    ca.src[3] = d_in[8];   ca.src[4] = d_in[9];   ca.src[5] = d_in[10];
    ca.src[6] = d_in[11];  ca.src[7] = d_in[12];  ca.src[8] = d_in[13];
    ca.src[9] = d_in[14];  ca.src[10] = d_in[15]; ca.src[11] = d_in[16];
    ca.src[12] = d_in[17]; ca.src[13] = d_in[18]; ca.src[14] = d_in[19];
    ca.src[15] = d_in[20]; ca.src[16] = d_in[21]; ca.src[17] = d_in[22];
    ca.src[18] = d_in[23]; ca.src[19] = d_in[24];
    convert_kernel<<<(CONV_TOTAL + 255) / 256, 256, 0, stream>>>(ca, flag, conv);
    swz_kernel<<<REC_TOTAL * 64 / 256, 256, 0, stream>>>(conv, swz);

    input_proj_kernel<<<N_NODES * 32 / 256, 256, 0, stream>>>(d_in[0], d_in[1], conv,
                                                              flag, h, hb);
    uc_kernel<<<3, 128, 0, stream>>>(conv, ubuf, cbuf);
    hist_kernel<<<N_EDGES / 256, 256, 0, stream>>>(dst, deg);
    scan_kernel<<<1, 1024, 0, stream>>>(deg, rowstart, cursor);
    scatter_kernel<<<N_EDGES / 256, 256, 0, stream>>>(src, dst, d_in[2], flag, cursor,
                                                      edges);

    for (int i = 0; i < 3; ++i) {
        const ushort_t* swzQKV = swz + (size_t)REC_QKV(i) * 512;
        const ushort_t* swzWL  = swz + (size_t)REC_WLIN(i) * 512;
        const ushort_t* swzF1  = swz + (size_t)REC_WF1(i) * 512;
        const ushort_t* swzF2  = swz + (size_t)REC_WF2(i) * 512;

        // Q bf16 + K/V fp8 packed (3-segment, 4-wave blocks)
        qkv_gemm<4><<<dim3(N_NODES / 64, 3), 256, 0, stream>>>(hb, swzQKV, Qh, KVf8);

        // attention -> hb (= HOUT) [N,128] bf16 (batched dual-gather main loop)
        agg_kernel<<<N_NODES, 64, 0, stream>>>(Qh, KVf8, rowstart, edges,
                                               ubuf + i * 128, cbuf + i * 128, hb);

        // fused layer tail, one wave per 16 rows (grid 2048)
        ffn_kernel<<<N_NODES / 16, 64, 0, stream>>>(
            hb, swzWL, swzF1, swzF2,
            conv + OFF_BLIN + i * 128, conv + OFF_G1 + i * 128, conv + OFF_BE1 + i * 128,
            conv + OFF_BF1 + i * 256,
            conv + OFF_BF2 + i * 128, conv + OFF_G2 + i * 128, conv + OFF_BE2 + i * 128,
            h, hb);
    }

    mean_part_kernel<<<N_NODES / 256, 256, 0, stream>>>(h, macc);
    finalize_kernel<<<1, 128, 0, stream>>>(macc, d_out, flag);
}